// Round 9
// baseline (267.182 us; speedup 1.0000x reference)
//
#include <hip/hip_runtime.h>
#include <cstdint>

#define HS 62
#define HX 248
#define HXW (HX * HX)  // 61504
#define HSW (HS * HS)  // 3844
#define HXP 256        // padded row stride for vv (128-B aligned rows)
#define HXWP (HX * HXP)  // 63488 padded plane

typedef __attribute__((ext_vector_type(8))) short bf16x8;
typedef __attribute__((ext_vector_type(4))) float f32x4;
typedef __attribute__((ext_vector_type(2))) float f32x2;

static __device__ __forceinline__ unsigned short f2bf(float f) {
  uint32_t u = __builtin_bit_cast(uint32_t, f);
  u += 0x7fff + ((u >> 16) & 1);  // RNE
  return (unsigned short)(u >> 16);
}
static __device__ __forceinline__ float bf2f(unsigned short u) {
  uint32_t x = (uint32_t)u << 16;
  return __builtin_bit_cast(float, x);
}
static __device__ __forceinline__ float bflo(uint32_t u) {
  return __builtin_bit_cast(float, u << 16);
}
static __device__ __forceinline__ float bfhi(uint32_t u) {
  return __builtin_bit_cast(float, u & 0xffff0000u);
}

// packed fp32 FMA: acc = a*b + acc (2 lanes of fp32, CDNA v_pk_fma_f32)
static __device__ __forceinline__ void pkfma(f32x2& acc, f32x2 a, f32x2 b) {
  asm("v_pk_fma_f32 %0, %1, %2, %0" : "+v"(acc) : "v"(a), "v"(b));
}
// packed f32->bf16 RNE convert: returns (bf16(lo) | bf16(hi)<<16)
static __device__ __forceinline__ uint32_t cvtpk(float lo, float hi) {
  uint32_t r;
  asm("v_cvt_pk_bf16_f32 %0, %1, %2" : "=v"(r) : "v"(lo), "v"(hi));
  return r;
}
// unpack u32 holding 2 bf16 -> packed f32 pair
static __device__ __forceinline__ f32x2 unp(uint32_t u) {
  f32x2 r;
  r.x = __builtin_bit_cast(float, u << 16);
  r.y = __builtin_bit_cast(float, u & 0xffff0000u);
  return r;
}

// ---------------------------------------------------------------------------
// Depthwise 3x3 scalar (62x62 tensors), fp32 out, bias+residual.
// ---------------------------------------------------------------------------
__global__ void dwconv3_kernel(const float* __restrict__ x, const float* __restrict__ w,
                               const float* __restrict__ bias, float* __restrict__ y,
                               int C, int H, int W, int total, int residual) {
  int i = blockIdx.x * 256 + threadIdx.x;
  if (i >= total) return;
  int wx = i % W;
  int t = i / W;
  int hy = t % H;
  int bc = t / H;
  int c = bc % C;
  const float* xb = x + (size_t)bc * H * W;
  const float* wc = w + c * 9;
  float s = bias ? bias[c] : 0.0f;
  for (int di = -1; di <= 1; di++) {
    int h2 = hy + di;
    if (h2 < 0 || h2 >= H) continue;
    for (int dj = -1; dj <= 1; dj++) {
      int w2 = wx + dj;
      if (w2 < 0 || w2 >= W) continue;
      s += xb[(size_t)h2 * W + w2] * wc[(di + 1) * 3 + (dj + 1)];
    }
  }
  if (residual) s += xb[(size_t)hy * W + wx];
  y[i] = s;
}

// ---------------------------------------------------------------------------
// Pack w_kv (fp32, 256x128) directly into bf16 MFMA B-fragment order.
// ---------------------------------------------------------------------------
__global__ void pack_wfrag_kernel(const float* __restrict__ w_kv,
                                  unsigned short* __restrict__ wf) {
  int i = blockIdx.x * 256 + threadIdx.x;  // 4096 threads x 8 shorts
  if (i >= 4096) return;
  int lane = i & 63;
  int f = i >> 6;
  int hq = f >> 4, ot = (f >> 2) & 3, kb = f & 3;
  int l15 = lane & 15, quad = lane >> 4;
  const float* src = w_kv + (size_t)(hq * 64 + ot * 16 + l15) * 128 + kb * 32 + quad * 8;
  unsigned short* dst = wf + (size_t)i * 8;
#pragma unroll
  for (int j = 0; j < 8; j++) dst[j] = f2bf(src[j]);
}

// ---------------------------------------------------------------------------
// Depthwise 3x3 q path: fp32 NCHW in -> bf16 NHWC out, pre-scaled by 32^-0.5.
// ---------------------------------------------------------------------------
__global__ void dwconv_q_kernel(const float* __restrict__ x, const float* __restrict__ w,
                                unsigned short* __restrict__ qn, int total) {
  int i = blockIdx.x * 256 + threadIdx.x;
  if (i >= total) return;
  int wx = i % HS;
  int t = i / HS;
  int hy = t % HS;
  int bc = t / HS;
  int c = bc & 127;
  int b = bc >> 7;
  const float* xb = x + (size_t)bc * HSW;
  const float* wc = w + c * 9;
  float s = 0.0f;
  for (int di = -1; di <= 1; di++) {
    int h2 = hy + di;
    if (h2 < 0 || h2 >= HS) continue;
    for (int dj = -1; dj <= 1; dj++) {
      int w2 = wx + dj;
      if (w2 < 0 || w2 >= HS) continue;
      s += xb[(size_t)h2 * HS + w2] * wc[(di + 1) * 3 + (dj + 1)];
    }
  }
  qn[((size_t)(b * HSW + hy * HS + wx)) * 128 + c] = f2bf(s * 0.17677669529663688f);
}

// ---------------------------------------------------------------------------
// FUSED step1+5, v2 (round-9 post-mortem fixes):
//   - XCD-chunked bijective block swizzle: vertical-halo rows reused in the
//     SAME XCD's L2 (round-9: round-robin put neighbors on different XCDs ->
//     FETCH 2x input).
//   - Phase-1 register diet: channels computed strictly sequentially (one
//     30-float row-set live), amdgpu_waves_per_eu(4) pins the 128-VGPR tier
//     (round-9: VGPR snapped to 56 -> latency-bound).
// Phase 2 unchanged (packed wf, 2-deep prefetch). Grid (961, 2), block 256.
// ---------------------------------------------------------------------------
__global__ __launch_bounds__(256) __attribute__((amdgpu_waves_per_eu(4)))
void dwconv1_fused_kernel(
    const float* __restrict__ x,        // (2,128,248,248) fp32 NCHW
    const float* __restrict__ wpos,     // (128,1,3,3)
    const float* __restrict__ bias,     // (128)
    const unsigned short* __restrict__ wf,  // packed B-fragments
    unsigned short* __restrict__ y) {   // tkv (2,61504,256) bf16 NHWC
  // bijective XCD chunk swizzle: 961 = 8*120 + 1
  int fid = blockIdx.x;
  int xcd = fid & 7, slot = fid >> 3;
  int gi = (xcd == 0 ? slot : 121 + (xcd - 1) * 120 + slot);
  int b = blockIdx.y;
  int p0 = gi * 64;
  int tid = threadIdx.x;
  int wave = tid >> 6, lane = tid & 63, quad = lane >> 4, l15 = lane & 15;
  __shared__ __align__(16) unsigned short bufA[64 * 136];  // 17,408 B

  // ---- phase 1: dwconv3 + residual -> bf16 -> bufA[px][c^swz] ----
  {
    int pxg = (tid & 7) * 8;           // local px group (8|248 -> single row)
    int c0 = (tid >> 3) * 4;           // channels c0..c0+3
    int flat = p0 + pxg;
    int row = flat / HX;
    int col = flat % HX;               // col+8 <= HX
    int swz = (tid & 7) << 3;
    bool top = (row == 0), bot = (row == HX - 1);
    int rm = top ? 0 : row - 1;
    int rp = bot ? HX - 1 : row + 1;
    int csbase = c0 ^ swz;

    // one channel at a time: 3x10 rows live (30 fp), o[8] out.
    auto do1 = [&](int c, float (&o)[8]) {
      const float* xb = x + ((size_t)(b * 128 + c)) * HXW;
      const float* wc = wpos + c * 9;
      float bv = bias[c];
      float A[10], B[10], C[10];
      auto loadrow = [&](int h2, float (&r)[10]) {
        const float* rowp = xb + (size_t)h2 * HX + col;
        float4 a = *(const float4*)rowp;
        float4 b2 = *(const float4*)(rowp + 4);
        r[1] = a.x;  r[2] = a.y;  r[3] = a.z;  r[4] = a.w;
        r[5] = b2.x; r[6] = b2.y; r[7] = b2.z; r[8] = b2.w;
        r[0] = (col > 0) ? rowp[-1] : 0.0f;
        r[9] = (col + 8 < HX) ? rowp[8] : 0.0f;
      };
      loadrow(rm, A); loadrow(row, B); loadrow(rp, C);
      if (top) {
#pragma unroll
        for (int k = 0; k < 10; k++) A[k] = 0.0f;
      }
      if (bot) {
#pragma unroll
        for (int k = 0; k < 10; k++) C[k] = 0.0f;
      }
      float u0 = wc[0], u1 = wc[1], u2 = wc[2], u3 = wc[3], u4 = wc[4],
            u5 = wc[5], u6 = wc[6], u7 = wc[7], u8 = wc[8];
#pragma unroll
      for (int k = 0; k < 8; k++) {
        float s = bv;
        s += u0 * A[k]; s += u1 * A[k + 1]; s += u2 * A[k + 2];
        s += u3 * B[k]; s += u4 * B[k + 1]; s += u5 * B[k + 2];
        s += u6 * C[k]; s += u7 * C[k + 1]; s += u8 * C[k + 2];
        o[k] = s + B[k + 1];
      }
    };

#pragma unroll 1
    for (int pair = 0; pair < 2; pair++) {
      int c = c0 + pair * 2;
      float oa[8], ob[8];
      do1(c, oa);
      do1(c + 1, ob);
      int cs = csbase + pair * 2;      // uint32-aligned
#pragma unroll
      for (int k = 0; k < 8; k++)
        *(uint32_t*)&bufA[(pxg + k) * 136 + cs] = cvtpk(oa[k], ob[k]);
    }
  }
  __syncthreads();

  // ---- phase 2: MFMA 1x1 conv (v8 pipeline, unchanged) ----
  bf16x8 A[4];
  {
    int px = wave * 16 + l15;
    int swz = ((px >> 3) & 7) << 3;
#pragma unroll
    for (int kb = 0; kb < 4; kb++)
      A[kb] = __builtin_bit_cast(bf16x8,
          *(const uint4*)&bufA[px * 136 + ((kb * 32 + quad * 8) ^ swz)]);
  }

  const f32x4 zf = {0.f, 0.f, 0.f, 0.f};
  const uint4* wfu = (const uint4*)wf;
  uint4 Bc[4], Bn[4];
  {
    const uint4* fb = wfu + lane;  // tile 0
    Bc[0] = fb[0]; Bc[1] = fb[64]; Bc[2] = fb[128]; Bc[3] = fb[192];
  }
  int orow = wave * 16 + quad * 4;      // D-row base (px)
#pragma unroll 1
  for (int h = 0; h < 2; h++) {
#pragma unroll
    for (int tt = 0; tt < 8; tt++) {
      int t = h * 8 + tt;
      if (t < 15) {  // prefetch next tile's 4 B-fragments
        const uint4* fb = wfu + (size_t)(t + 1) * 256 + lane;
        Bn[0] = fb[0]; Bn[1] = fb[64]; Bn[2] = fb[128]; Bn[3] = fb[192];
      }
      f32x4 D = zf;
      D = __builtin_amdgcn_mfma_f32_16x16x32_bf16(A[0], __builtin_bit_cast(bf16x8, Bc[0]), D, 0, 0, 0);
      D = __builtin_amdgcn_mfma_f32_16x16x32_bf16(A[1], __builtin_bit_cast(bf16x8, Bc[1]), D, 0, 0, 0);
      D = __builtin_amdgcn_mfma_f32_16x16x32_bf16(A[2], __builtin_bit_cast(bf16x8, Bc[2]), D, 0, 0, 0);
      D = __builtin_amdgcn_mfma_f32_16x16x32_bf16(A[3], __builtin_bit_cast(bf16x8, Bc[3]), D, 0, 0, 0);
      int col = tt * 16 + l15;
#pragma unroll
      for (int r = 0; r < 4; r++) {
        int row = orow + r;
        bufA[row * 136 + (col ^ (((row >> 3) & 7) << 3))] = f2bf(D[r]);
      }
      if (t < 15) {
#pragma unroll
        for (int k = 0; k < 4; k++) Bc[k] = Bn[k];
      }
    }
    __syncthreads();
    {  // flush this o-half: 64 px x 128 o, coalesced
      int px = tid >> 2, og = (tid & 3) * 32;
      int swz = ((px >> 3) & 7) << 3;
      uint4* dstp = (uint4*)(y + ((size_t)b * HXW + p0 + px) * 256 + h * 128 + og);
#pragma unroll
      for (int j = 0; j < 4; j++)
        dstp[j] = *(const uint4*)&bufA[px * 136 + ((og + j * 8) ^ swz)];
    }
    __syncthreads();
  }
}

// ---------------------------------------------------------------------------
// Fused depthwise 3x3 K/V from bf16 NHWC tkv — v4: 2-channel lanes, 512-thr
// blocks, fused row-pair column streaming. Grid (496, 2), block 512.
// ---------------------------------------------------------------------------
template <bool VT, bool VB>
static __device__ __forceinline__ void dwkv_rowpair(
    const unsigned short* __restrict__ rm1, const unsigned short* __restrict__ r0,
    const unsigned short* __restrict__ r1, const unsigned short* __restrict__ r2,
    const f32x2 (&wp)[9], int px0, f32x2 (&a0)[8], f32x2 (&a1)[8]) {
  const f32x2 z2 = {0.f, 0.f};
#pragma unroll
  for (int p = 0; p < 8; p++) { a0[p] = z2; a1[p] = z2; }
#pragma unroll
  for (int j = 0; j < 10; j++) {
    int xcol = px0 - 1 + j;
    int xc = xcol;
    if (j == 0) xc = (xcol < 0) ? 0 : xcol;
    if (j == 9) xc = (xcol > HX - 1) ? HX - 1 : xcol;
    size_t off = (size_t)xc * 256;
    uint32_t um1 = 0, u0, u1, u2 = 0;
    u0 = *(const uint32_t*)(r0 + off);
    u1 = *(const uint32_t*)(r1 + off);
    if constexpr (VT) um1 = *(const uint32_t*)(rm1 + off);
    if constexpr (VB) u2 = *(const uint32_t*)(r2 + off);
    if (j == 0 || j == 9) {  // only edge columns can be out of range
      bool oob = (j == 0) ? (xcol < 0) : (xcol > HX - 1);
      if (oob) { um1 = 0u; u0 = 0u; u1 = 0u; u2 = 0u; }
    }
    f32x2 dm1, d0 = unp(u0), d1 = unp(u1), d2;
    if constexpr (VT) dm1 = unp(um1);
    if constexpr (VB) d2 = unp(u2);
    if (j <= 7) {
      if constexpr (VT) pkfma(a0[j], wp[0], dm1);
      pkfma(a0[j], wp[3], d0);
      pkfma(a0[j], wp[6], d1);
      pkfma(a1[j], wp[0], d0);
      pkfma(a1[j], wp[3], d1);
      if constexpr (VB) pkfma(a1[j], wp[6], d2);
    }
    if (j >= 1 && j <= 8) {
      if constexpr (VT) pkfma(a0[j - 1], wp[1], dm1);
      pkfma(a0[j - 1], wp[4], d0);
      pkfma(a0[j - 1], wp[7], d1);
      pkfma(a1[j - 1], wp[1], d0);
      pkfma(a1[j - 1], wp[4], d1);
      if constexpr (VB) pkfma(a1[j - 1], wp[7], d2);
    }
    if (j >= 2) {
      if constexpr (VT) pkfma(a0[j - 2], wp[2], dm1);
      pkfma(a0[j - 2], wp[5], d0);
      pkfma(a0[j - 2], wp[8], d1);
      pkfma(a1[j - 2], wp[2], d0);
      pkfma(a1[j - 2], wp[5], d1);
      if constexpr (VB) pkfma(a1[j - 2], wp[8], d2);
    }
  }
}

#define VTS 72                    // vt channel stride (shorts): 144 B, 16-B aligned
#define VTROW (128 * VTS + 16)    // vt row stride (shorts), +16 shifts banks

__global__ __launch_bounds__(512) __attribute__((amdgpu_waves_per_eu(4)))
void dwconv_kv_kernel(const unsigned short* __restrict__ tkv,
                      const float* __restrict__ w,
                      unsigned short* __restrict__ kT,
                      unsigned short* __restrict__ vv) {
  int fid = blockIdx.x;
  int xcd = fid & 7, slot = fid >> 3;
  int gi = xcd * 62 + slot;          // 0..495
  int strip = gi / 124;              // 0..3
  int g = gi % 124;                  // row-pair index
  int b = blockIdx.y;
  int x0 = strip * 64;
  int tid = threadIdx.x;
  int cl = tid & 127;                // channel lane: ch = 2*cl, 2*cl+1
  int pg = tid >> 7;                 // 0..3 px-group (wave-pair uniform)
  int ch0 = cl * 2;
  int hy0 = g * 2;

  f32x2 wp[9];
#pragma unroll
  for (int t = 0; t < 9; t++) {
    wp[t].x = w[ch0 * 9 + t];
    wp[t].y = w[(ch0 + 1) * 9 + t];
  }

  __shared__ __align__(16) unsigned short vt[2 * VTROW];  // 36,928 B

  const unsigned short* r0 = tkv + (size_t)b * HXW * 256 + (size_t)hy0 * (HX * 256) + ch0;
  const unsigned short* r1 = r0 + HX * 256;
  const unsigned short* rm1 = r0 - HX * 256;   // deref only when VT
  const unsigned short* r2 = r1 + HX * 256;    // deref only when VB
  bool isK = (cl < 64);
  int c0 = ch0 - 128;                // V-lane channel base

#pragma unroll 1
  for (int half = 0; half < 2; half++) {
    int px0 = x0 + pg * 16 + half * 8;
    if (px0 < HX) {  // strip 3 / pg 3 / half 1 is pure pad: skip
      f32x2 a0[8], a1[8];
      if (g == 0)        dwkv_rowpair<false, true >(rm1, r0, r1, r2, wp, px0, a0, a1);
      else if (g == 123) dwkv_rowpair<true,  false>(rm1, r0, r1, r2, wp, px0, a0, a1);
      else               dwkv_rowpair<true,  true >(rm1, r0, r1, r2, wp, px0, a0, a1);

      if (isK) {  // K rows: direct NHWC store, 2 ch packed per dword
        unsigned short* kb0 = kT + ((size_t)b * HXW + (size_t)hy0 * HX + px0) * 128 + ch0;
        unsigned short* kb1 = kb0 + (size_t)HX * 128;
#pragma unroll
        for (int p = 0; p < 8; p++) {
          *(uint32_t*)(kb0 + (size_t)p * 128) = cvtpk(a0[p].x, a0[p].y);
          *(uint32_t*)(kb1 + (size_t)p * 128) = cvtpk(a1[p].x, a1[p].y);
        }
      } else {    // V rows: stage transposed [row][ch][px] into LDS
        int pxr = pg * 16 + half * 8;
        unsigned short* v0 = vt + c0 * VTS + pxr;        // ch c0, row 0
        unsigned short* v1 = v0 + VTS;                   // ch c0+1
        uint2 d;
        d.x = cvtpk(a0[0].x, a0[1].x); d.y = cvtpk(a0[2].x, a0[3].x);
        *(uint2*)(v0) = d;
        d.x = cvtpk(a0[4].x, a0[5].x); d.y = cvtpk(a0[6].x, a0[7].x);
        *(uint2*)(v0 + 4) = d;
        d.x = cvtpk(a0[0].y, a0[1].y); d.y = cvtpk(a0[2].y, a0[3].y);
        *(uint2*)(v1) = d;
        d.x = cvtpk(a0[4].y, a0[5].y); d.y = cvtpk(a0[6].y, a0[7].y);
        *(uint2*)(v1 + 4) = d;
        d.x = cvtpk(a1[0].x, a1[1].x); d.y = cvtpk(a1[2].x, a1[3].x);
        *(uint2*)(v0 + VTROW) = d;
        d.x = cvtpk(a1[4].x, a1[5].x); d.y = cvtpk(a1[6].x, a1[7].x);
        *(uint2*)(v0 + VTROW + 4) = d;
        d.x = cvtpk(a1[0].y, a1[1].y); d.y = cvtpk(a1[2].y, a1[3].y);
        *(uint2*)(v1 + VTROW) = d;
        d.x = cvtpk(a1[4].y, a1[5].y); d.y = cvtpk(a1[6].y, a1[7].y);
        *(uint2*)(v1 + VTROW + 4) = d;
      }
    }
  }
  __syncthreads();
  {  // cooperative NCHW store of both V rows (full 128-B lines, padded rows)
    int ch = tid >> 2;
    int row = (tid >> 1) & 1;
    int ph = (tid & 1) * 32;
    const unsigned short* srcv = vt + row * VTROW + ch * VTS + ph;
    unsigned short* dst = vv + (size_t)(b * 128 + ch) * HXWP + (size_t)(hy0 + row) * HXP + x0 + ph;
#pragma unroll
    for (int j = 0; j < 4; j++)
      *(uint4*)(dst + j * 8) = *(const uint4*)(srcv + j * 8);
  }
}

// ---------------------------------------------------------------------------
// 1x1 conv tiled SGEMM (fp32) — small tensors (q path, output projection).
// ---------------------------------------------------------------------------
template <int O>
__global__ __launch_bounds__(256) void conv1_kernel(const float* __restrict__ x,
                                                    const float* __restrict__ w,
                                                    float* __restrict__ y, int HW) {
  constexpr int K = 128;
  constexpr int BK = 32;
  __shared__ __align__(16) float ws_s[BK][64];
  __shared__ __align__(16) float xs_s[BK][64];
  int b = blockIdx.z;
  int o0 = blockIdx.y * 64;
  int p0 = blockIdx.x * 64;
  const float* xb = x + (size_t)b * K * HW;
  int tx = threadIdx.x & 15;
  int ty = threadIdx.x >> 4;
  float acc[4][4] = {};
  int lo = threadIdx.x >> 2;
  int lk = (threadIdx.x & 3) * 8;
  int lc = threadIdx.x >> 3;
  int lp = (threadIdx.x & 7) * 8;

  for (int k0 = 0; k0 < K; k0 += BK) {
    __syncthreads();
    {
      const float* wp = w + (size_t)(o0 + lo) * K + k0 + lk;
      float4 a = *(const float4*)wp;
      float4 bq = *(const float4*)(wp + 4);
      ws_s[lk + 0][lo] = a.x;  ws_s[lk + 1][lo] = a.y;
      ws_s[lk + 2][lo] = a.z;  ws_s[lk + 3][lo] = a.w;
      ws_s[lk + 4][lo] = bq.x; ws_s[lk + 5][lo] = bq.y;
      ws_s[lk + 6][lo] = bq.z; ws_s[lk + 7][lo] = bq.w;
    }
    {
      int p = p0 + lp;
      const float* xp = xb + (size_t)(k0 + lc) * HW;
      float4 a, bq;
      if (p + 7 < HW) {
        a = *(const float4*)(xp + p);
        bq = *(const float4*)(xp + p + 4);
      } else {
        float tv[8];
#pragma unroll
        for (int j = 0; j < 8; j++) tv[j] = (p + j < HW) ? xp[p + j] : 0.0f;
        a = make_float4(tv[0], tv[1], tv[2], tv[3]);
        bq = make_float4(tv[4], tv[5], tv[6], tv[7]);
      }
      *(float4*)&xs_s[lc][lp] = a;
      *(float4*)&xs_s[lc][lp + 4] = bq;
    }
    __syncthreads();
#pragma unroll
    for (int k = 0; k < BK; k++) {
      float4 wv = *(const float4*)&ws_s[k][ty * 4];
      float4 xv = *(const float4*)&xs_s[k][tx * 4];
      acc[0][0] += wv.x * xv.x; acc[0][1] += wv.x * xv.y; acc[0][2] += wv.x * xv.z; acc[0][3] += wv.x * xv.w;
      acc[1][0] += wv.y * xv.x; acc[1][1] += wv.y * xv.y; acc[1][2] += wv.y * xv.z; acc[1][3] += wv.y * xv.w;
      acc[2][0] += wv.z * xv.x; acc[2][1] += wv.z * xv.y; acc[2][2] += wv.z * xv.z; acc[2][3] += wv.z * xv.w;
      acc[3][0] += wv.w * xv.x; acc[3][1] += wv.w * xv.y; acc[3][2] += wv.w * xv.z; acc[3][3] += wv.w * xv.w;
    }
  }
  int p = p0 + tx * 4;
  float* yb = y + (size_t)b * O * HW + (size_t)(o0 + ty * 4) * HW;
#pragma unroll
  for (int j = 0; j < 4; j++) {
    float* yr = yb + (size_t)j * HW + p;
    if (p + 3 < HW) {
      *(float4*)yr = make_float4(acc[j][0], acc[j][1], acc[j][2], acc[j][3]);
    } else {
#pragma unroll
      for (int e = 0; e < 4; e++) if (p + e < HW) yr[e] = acc[j][e];
    }
  }
}

// ---------------------------------------------------------------------------
// MFMA windowed attention v3 — one head per block. Grid 800 = (b,4h,100n),
// XCD-swizzled so each XCD owns one (b,h) slice x all windows. 256 thr =
// 4 oct-waves x 8 key rows. Single-pass epilogue, direct normalized output.
// ---------------------------------------------------------------------------
__global__ __launch_bounds__(256) void attn_mfma_kernel(
    const unsigned short* __restrict__ qn,   // (2,62,62,128) bf16, pre-scaled
    const unsigned short* __restrict__ kT,   // (2,248,248,128) bf16 NHWC
    const unsigned short* __restrict__ vp,   // (2,128,248,256p) bf16 NCHW padded
    float* __restrict__ o) {                 // (2,100,128,64)
  int fid = blockIdx.x;
  int xcd = fid & 7, slot = fid >> 3;        // slot 0..99
  int lin = xcd * 100 + slot;
  int n = lin % 100;
  int bh = lin / 100;                        // 0..7
  int h = bh & 3, b = bh >> 2;
  int wi = n / 10, wj = n % 10;
  int wave = threadIdx.x >> 6;               // oct 0..3
  int oct = wave;
  int lane = threadIdx.x & 63;
  int quad = lane >> 4;
  int l15 = lane & 15;
  int y0 = 24 * wi, x0 = 24 * wj;

  __shared__ __align__(16) unsigned short lds[16896];  // 33,792 B
  unsigned short* Pw = lds + wave * 2560;              // [q][40keys] 5KB/wave

  bf16x8 QB[4];
#pragma unroll
  for (int nt = 0; nt < 4; nt++) {
    int qq = nt * 16 + l15;
    int qy = 6 * wi + (qq >> 3), qx = 6 * wj + (qq & 7);
    QB[nt] = __builtin_bit_cast(bf16x8,
        *(const uint4*)(qn + ((size_t)(b * HSW + qy * HS + qx)) * 128 + h * 32 + quad * 8));
  }

  f32x4 Oacc[2][4];
#pragma unroll
  for (int a = 0; a < 2; a++)
#pragma unroll
    for (int c = 0; c < 4; c++) Oacc[a][c] = f32x4{0.f, 0.f, 0.f, 0.f};
  float lsum[4] = {0.f, 0.f, 0.f, 0.f};

  const unsigned short* kb = kT + (size_t)b * HXW * 128 + h * 32;
  const unsigned short* vb = vp + ((size_t)(b * 128 + h * 32)) * HXWP;
  const f32x4 zf = {0.f, 0.f, 0.f, 0.f};

#define LOADROW(r, K0, K1, V0, V1)                                              \
  {                                                                             \
    int y = y0 + (r);                                                           \
    const unsigned short* krow = kb + ((size_t)(y * HX + x0)) * 128;            \
    K0 = *(const uint4*)(krow + (size_t)l15 * 128 + quad * 8);                  \
    K1 = *(const uint4*)(krow + (size_t)(16 + l15) * 128 + quad * 8);           \
    const unsigned short* vrow = vb + (size_t)y * HXP + x0 + quad * 8;          \
    V0 = *(const uint4*)(vrow + (size_t)l15 * HXWP);                            \
    V1 = *(const uint4*)(vrow + (size_t)(16 + l15) * HXWP);                     \
  }

  auto compute = [&](uint4 k0, uint4 k1, uint4 v0, uint4 v1) {
    bf16x8 KA0 = __builtin_bit_cast(bf16x8, k0);
    bf16x8 KA1 = __builtin_bit_cast(bf16x8, k1);
    bf16x8 VA0 = __builtin_bit_cast(bf16x8, v0);
    bf16x8 VA1 = __builtin_bit_cast(bf16x8, v1);
    f32x4 S[2][4];
#pragma unroll
    for (int nt = 0; nt < 4; nt++) {
      S[0][nt] = __builtin_amdgcn_mfma_f32_16x16x32_bf16(KA0, QB[nt], zf, 0, 0, 0);
      S[1][nt] = __builtin_amdgcn_mfma_f32_16x16x32_bf16(KA1, QB[nt], zf, 0, 0, 0);
    }
#pragma unroll
    for (int nt = 0; nt < 4; nt++) {
      float pv[2][4];
      float cs = 0.f;
#pragma unroll
      for (int mt = 0; mt < 2; mt++)
#pragma unroll
        for (int r = 0; r < 4; r++) {
          pv[mt][r] = __expf(S[mt][nt][r]);
          cs += pv[mt][r];
        }
      lsum[nt] += cs;
#pragma unroll
      for (int mt = 0; mt < 2; mt++) {
        uint2 d;
        d.x = (uint32_t)f2bf(pv[mt][0]) | ((uint32_t)f2bf(pv[mt][1]) << 16);
        d.y = (uint32_t)f2bf(pv[mt][2]) | ((uint32_t)f2bf(pv[mt][3]) << 16);
        *(uint2*)(Pw + (16 * nt + l15) * 40 + 16 * mt + quad * 4) = d;
      }
    }
#pragma unroll
    for (int nt = 0; nt < 4; nt++) {
      bf16x8 PB = __builtin_bit_cast(bf16x8, *(const uint4*)(Pw + (16 * nt + l15) * 40 + quad * 8));
      Oacc[0][nt] = __builtin_amdgcn_mfma_f32_16x16x32_bf16(VA0, PB, Oacc[0][nt], 0, 0, 0);
      Oacc[1][nt] = __builtin_amdgcn_mfma_f32_16x16x32_bf16(VA1, PB, Oacc[1][nt], 0, 0, 0);
    }
  };

  int rbase = oct * 8;
  uint4 kA0, kA1, vA0, vA1, kB0, kB1, vB0, vB1;
  LOADROW(rbase + 0, kA0, kA1, vA0, vA1);
  LOADROW(rbase + 1, kB0, kB1, vB0, vB1);
#pragma unroll 1
  for (int r = 0; r < 8; r += 2) {
    compute(kA0, kA1, vA0, vA1);
    {
      int rn = (r + 2 < 8) ? (r + 2) : 6;  // clamped, branch-free
      LOADROW(rbase + rn, kA0, kA1, vA0, vA1);
    }
    compute(kB0, kB1, vB0, vB1);
    {
      int rn = (r + 3 < 8) ? (r + 3) : 7;  // clamped, branch-free
      LOADROW(rbase + rn, kB0, kB1, vB0, vB1);
    }
  }
#undef LOADROW

#pragma unroll
  for (int nt = 0; nt < 4; nt++) {
    lsum[nt] += __shfl_xor(lsum[nt], 16, 64);
    lsum[nt] += __shfl_xor(lsum[nt], 32, 64);
  }

  float* mO = (float*)lds;                 // [oct][32ch][64q]  32 KB
  float* mL = (float*)(lds + 16384);       // [oct][64q]  1 KB
  __syncthreads();  // all Pw reads done before overwrite
#pragma unroll
  for (int mt = 0; mt < 2; mt++)
#pragma unroll
    for (int nt = 0; nt < 4; nt++)
#pragma unroll
      for (int r = 0; r < 4; r++)
        mO[oct * 2048 + (16 * mt + quad * 4 + r) * 64 + 16 * nt + l15] = Oacc[mt][nt][r];
  if (quad == 0) {
#pragma unroll
    for (int nt = 0; nt < 4; nt++) mL[oct * 64 + nt * 16 + l15] = lsum[nt];
  }
  __syncthreads();
  {
    int q = threadIdx.x & 63;
    int cg = threadIdx.x >> 6;  // 0..3 -> 8 ch each
    float inv = 1.0f / (mL[q] + mL[64 + q] + mL[128 + q] + mL[192 + q]);
    float* ob = o + (((size_t)(b * 100 + n)) * 128 + h * 32 + cg * 8) * 64 + q;
#pragma unroll
    for (int e = 0; e < 8; e++) {
      int ch = cg * 8 + e;
      float s = mO[ch * 64 + q] + mO[2048 + ch * 64 + q] +
                mO[4096 + ch * 64 + q] + mO[6144 + ch * 64 + q];
      ob[(size_t)e * 64] = s * inv;
    }
  }
}

// ---------------------------------------------------------------------------
// Reverse: scatter-average overlapping 8x8 windows (step 6) into (2,128,62,62)
// ---------------------------------------------------------------------------
__global__ void reverse_kernel(const float* __restrict__ win, float* __restrict__ out) {
  int i = blockIdx.x * 256 + threadIdx.x;
  const int total = 2 * 128 * HSW;
  if (i >= total) return;
  int x = i % HS;
  int t = i / HS;
  int y = t % HS;
  t /= HS;
  int c = t % 128;
  int b = t / 128;
  int wi0 = (y >= 7) ? (y - 2) / 6 : 0;
  int wi1 = min(9, y / 6);
  int wj0 = (x >= 7) ? (x - 2) / 6 : 0;
  int wj1 = min(9, x / 6);
  float s = 0.0f;
  for (int wi = wi0; wi <= wi1; wi++)
    for (int wj = wj0; wj <= wj1; wj++) {
      int di = y - 6 * wi, dj = x - 6 * wj;
      s += win[(((size_t)(b * 100 + wi * 10 + wj)) * 128 + c) * 64 + di * 8 + dj];
    }
  float cnt = (float)((wi1 - wi0 + 1) * (wj1 - wj0 + 1));
  out[i] = s / cnt;
}

// ---------------------------------------------------------------------------
extern "C" void kernel_launch(void* const* d_in, const int* in_sizes, int n_in,
                              void* d_out, int out_size, void* d_ws, size_t ws_size,
                              hipStream_t stream) {
  const float* x      = (const float*)d_in[0];
  const float* sp     = (const float*)d_in[1];
  const float* w_pos  = (const float*)d_in[2];
  const float* b_pos  = (const float*)d_in[3];
  const float* w_q    = (const float*)d_in[4];
  const float* w_qdw  = (const float*)d_in[5];
  const float* w_kv   = (const float*)d_in[6];
  const float* w_kvdw = (const float*)d_in[7];
  const float* w_out  = (const float*)d_in[8];
  float* out = (float*)d_out;

  const size_t N_x   = (size_t)2 * 128 * HXW;   // 15,745,024 (shorts for kT)
  const size_t N_vp  = (size_t)2 * 128 * HXWP;  // 16,252,928 (padded vv, shorts)
  const size_t N_s   = (size_t)2 * 128 * HSW;
  const size_t N_att = (size_t)2 * 100 * 128 * 64;

  float* ws = (float*)d_ws;
  // shorts-based layout (all counts even -> float-aligned):
  unsigned short* kT  = (unsigned short*)ws;          // N_x shorts
  unsigned short* vv  = kT + N_x;                     // N_vp shorts (padded rows)
  unsigned short* tkv = vv + N_vp;                    // 2*N_x shorts
  float* att = (float*)tkv;                           // reuse (tkv dead after step 6)
  float* rev = att + N_att;
  float* spp = (float*)(tkv + 2 * N_x);
  float* tq  = spp + N_s;
  unsigned short* qn  = (unsigned short*)(tq + N_s);  // N_s shorts
  unsigned short* wkb = qn + N_s;                     // 32768 shorts (frag-packed)
  (void)ws_size; (void)in_sizes; (void)n_in; (void)out_size;

  // 0. wkb = bf16 fragment-packed w_kv
  pack_wfrag_kernel<<<16, 256, 0, stream>>>(w_kv, wkb);
  // 1+5 fused: tkv = bf16_nhwc(conv1(bf16(x + dwconv3(x)), wkb))
  {
    dim3 grid(961, 2);
    dwconv1_fused_kernel<<<grid, 256, 0, stream>>>(x, w_pos, b_pos, wkb, tkv);
  }
  // 2. spp = sp + dwconv3(sp, w_pos, b_pos)
  {
    int total = (int)N_s;
    dwconv3_kernel<<<(total + 255) / 256, 256, 0, stream>>>(sp, w_pos, b_pos, spp, 128, HS, HS, total, 1);
  }
  // 3. tq = conv1(spp, w_q)
  {
    int HW = HSW;
    dim3 grid((HW + 63) / 64, 2, 2);
    conv1_kernel<128><<<grid, 256, 0, stream>>>(spp, w_q, tq, HW);
  }
  // 4. qn = bf16_nhwc(dwconv3(tq, w_qdw)) * 32^-0.5
  {
    int total = (int)N_s;
    dwconv_q_kernel<<<(total + 255) / 256, 256, 0, stream>>>(tq, w_qdw, qn, total);
  }
  // 6. kT (NHWC) + vv (NCHW padded) = bf16(dwconv3(tkv, w_kvdw))
  {
    dim3 grid(496, 2);
    dwconv_kv_kernel<<<grid, 512, 0, stream>>>(tkv, w_kvdw, kT, vv);
  }
  // 7. attention -> att (2,100,128,64)   (800 one-head blocks, XCD-swizzled)
  {
    attn_mfma_kernel<<<800, 256, 0, stream>>>(qn, kT, vv, att);
  }
  // 8. rev = reverse(att)
  {
    int total = (int)N_s;
    reverse_kernel<<<(total + 255) / 256, 256, 0, stream>>>(att, rev);
  }
  // 9. out = conv1(rev, w_out)
  {
    int HW = HSW;
    dim3 grid((HW + 63) / 64, 2, 2);
    conv1_kernel<128><<<grid, 256, 0, stream>>>(rev, w_out, out, HW);
  }
}

// Round 10
// 266.893 us; speedup vs baseline: 1.0011x; 1.0011x over previous
//
#include <hip/hip_runtime.h>
#include <cstdint>

#define HS 62
#define HX 248
#define HXW (HX * HX)  // 61504
#define HSW (HS * HS)  // 3844
#define HXP 256        // padded row stride for vv (128-B aligned rows)
#define HXWP (HX * HXP)  // 63488 padded plane

typedef __attribute__((ext_vector_type(8))) short bf16x8;
typedef __attribute__((ext_vector_type(4))) float f32x4;
typedef __attribute__((ext_vector_type(2))) float f32x2;

static __device__ __forceinline__ unsigned short f2bf(float f) {
  uint32_t u = __builtin_bit_cast(uint32_t, f);
  u += 0x7fff + ((u >> 16) & 1);  // RNE
  return (unsigned short)(u >> 16);
}
static __device__ __forceinline__ float bf2f(unsigned short u) {
  uint32_t x = (uint32_t)u << 16;
  return __builtin_bit_cast(float, x);
}
static __device__ __forceinline__ float bflo(uint32_t u) {
  return __builtin_bit_cast(float, u << 16);
}
static __device__ __forceinline__ float bfhi(uint32_t u) {
  return __builtin_bit_cast(float, u & 0xffff0000u);
}

// packed fp32 FMA: acc = a*b + acc (2 lanes of fp32, CDNA v_pk_fma_f32)
static __device__ __forceinline__ void pkfma(f32x2& acc, f32x2 a, f32x2 b) {
  asm("v_pk_fma_f32 %0, %1, %2, %0" : "+v"(acc) : "v"(a), "v"(b));
}
// packed f32->bf16 RNE convert: returns (bf16(lo) | bf16(hi)<<16)
static __device__ __forceinline__ uint32_t cvtpk(float lo, float hi) {
  uint32_t r;
  asm("v_cvt_pk_bf16_f32 %0, %1, %2" : "=v"(r) : "v"(lo), "v"(hi));
  return r;
}
// unpack u32 holding 2 bf16 -> packed f32 pair
static __device__ __forceinline__ f32x2 unp(uint32_t u) {
  f32x2 r;
  r.x = __builtin_bit_cast(float, u << 16);
  r.y = __builtin_bit_cast(float, u & 0xffff0000u);
  return r;
}

// ---------------------------------------------------------------------------
// Depthwise 3x3 scalar (62x62 tensors), fp32 out, bias+residual.
// ---------------------------------------------------------------------------
__global__ void dwconv3_kernel(const float* __restrict__ x, const float* __restrict__ w,
                               const float* __restrict__ bias, float* __restrict__ y,
                               int C, int H, int W, int total, int residual) {
  int i = blockIdx.x * 256 + threadIdx.x;
  if (i >= total) return;
  int wx = i % W;
  int t = i / W;
  int hy = t % H;
  int bc = t / H;
  int c = bc % C;
  const float* xb = x + (size_t)bc * H * W;
  const float* wc = w + c * 9;
  float s = bias ? bias[c] : 0.0f;
  for (int di = -1; di <= 1; di++) {
    int h2 = hy + di;
    if (h2 < 0 || h2 >= H) continue;
    for (int dj = -1; dj <= 1; dj++) {
      int w2 = wx + dj;
      if (w2 < 0 || w2 >= W) continue;
      s += xb[(size_t)h2 * W + w2] * wc[(di + 1) * 3 + (dj + 1)];
    }
  }
  if (residual) s += xb[(size_t)hy * W + wx];
  y[i] = s;
}

// ---------------------------------------------------------------------------
// Pack w_kv (fp32, 256x128) directly into bf16 MFMA B-fragment order.
// ---------------------------------------------------------------------------
__global__ void pack_wfrag_kernel(const float* __restrict__ w_kv,
                                  unsigned short* __restrict__ wf) {
  int i = blockIdx.x * 256 + threadIdx.x;  // 4096 threads x 8 shorts
  if (i >= 4096) return;
  int lane = i & 63;
  int f = i >> 6;
  int hq = f >> 4, ot = (f >> 2) & 3, kb = f & 3;
  int l15 = lane & 15, quad = lane >> 4;
  const float* src = w_kv + (size_t)(hq * 64 + ot * 16 + l15) * 128 + kb * 32 + quad * 8;
  unsigned short* dst = wf + (size_t)i * 8;
#pragma unroll
  for (int j = 0; j < 8; j++) dst[j] = f2bf(src[j]);
}

// ---------------------------------------------------------------------------
// Depthwise 3x3 q path: fp32 NCHW in -> bf16 NHWC out, pre-scaled by 32^-0.5.
// ---------------------------------------------------------------------------
__global__ void dwconv_q_kernel(const float* __restrict__ x, const float* __restrict__ w,
                                unsigned short* __restrict__ qn, int total) {
  int i = blockIdx.x * 256 + threadIdx.x;
  if (i >= total) return;
  int wx = i % HS;
  int t = i / HS;
  int hy = t % HS;
  int bc = t / HS;
  int c = bc & 127;
  int b = bc >> 7;
  const float* xb = x + (size_t)bc * HSW;
  const float* wc = w + c * 9;
  float s = 0.0f;
  for (int di = -1; di <= 1; di++) {
    int h2 = hy + di;
    if (h2 < 0 || h2 >= HS) continue;
    for (int dj = -1; dj <= 1; dj++) {
      int w2 = wx + dj;
      if (w2 < 0 || w2 >= HS) continue;
      s += xb[(size_t)h2 * HS + w2] * wc[(di + 1) * 3 + (dj + 1)];
    }
  }
  qn[((size_t)(b * HSW + hy * HS + wx)) * 128 + c] = f2bf(s * 0.17677669529663688f);
}

// ---------------------------------------------------------------------------
// FUSED step1+5, v3 (round-10 post-mortem fix):
//   - v2's FETCH fix (XCD-chunked bijective swizzle) retained: 33 MB fetch.
//   - Phase 1 was latency-bound (VGPR 52, 4 serialized load->compute chains,
//     VALUBusy 12%). v3: ALL 12 rows (4ch x 3rows x 10 fp = 120 regs, fully
//     static indexing) loaded in one straight-line burst BEFORE any compute
//     (the dwconv8x2 fat-thread pattern). waves_per_eu attr REMOVED so the
//     allocator may use the ~160-VGPR/3-wave tier instead of squeezing.
// Phase 2 unchanged (packed wf, 2-deep prefetch). Grid (961, 2), block 256.
// ---------------------------------------------------------------------------
__global__ __launch_bounds__(256)
void dwconv1_fused_kernel(
    const float* __restrict__ x,        // (2,128,248,248) fp32 NCHW
    const float* __restrict__ wpos,     // (128,1,3,3)
    const float* __restrict__ bias,     // (128)
    const unsigned short* __restrict__ wf,  // packed B-fragments
    unsigned short* __restrict__ y) {   // tkv (2,61504,256) bf16 NHWC
  // bijective XCD chunk swizzle: 961 = 8*120 + 1
  int fid = blockIdx.x;
  int xcd = fid & 7, slot = fid >> 3;
  int gi = (xcd == 0 ? slot : 121 + (xcd - 1) * 120 + slot);
  int b = blockIdx.y;
  int p0 = gi * 64;
  int tid = threadIdx.x;
  int wave = tid >> 6, lane = tid & 63, quad = lane >> 4, l15 = lane & 15;
  __shared__ __align__(16) unsigned short bufA[64 * 136];  // 17,408 B

  // ---- phase 1: dwconv3 + residual -> bf16 -> bufA[px][c^swz] ----
  {
    int pxg = (tid & 7) * 8;           // local px group (8|248 -> single row)
    int c0 = (tid >> 3) * 4;           // channels c0..c0+3
    int flat = p0 + pxg;
    int row = flat / HX;
    int col = flat % HX;               // col+8 <= HX
    int swz = (tid & 7) << 3;
    bool top = (row == 0), bot = (row == HX - 1);
    int rm = top ? 0 : row - 1;
    int rp = bot ? HX - 1 : row + 1;
    int csbase = c0 ^ swz;
    const float* xb = x + ((size_t)(b * 128 + c0)) * HXW;

    // R[ch][vrow 0=up,1=mid,2=dn][10] — fully static after unroll -> VGPRs.
    float R[4][3][10];
#pragma unroll
    for (int cc = 0; cc < 4; cc++) {
      const float* xc = xb + (size_t)cc * HXW;
#pragma unroll
      for (int v = 0; v < 3; v++) {
        int h2 = (v == 0) ? rm : ((v == 1) ? row : rp);
        const float* rowp = xc + (size_t)h2 * HX + col;
        float4 a = *(const float4*)rowp;
        float4 b2 = *(const float4*)(rowp + 4);
        R[cc][v][1] = a.x;  R[cc][v][2] = a.y;  R[cc][v][3] = a.z;  R[cc][v][4] = a.w;
        R[cc][v][5] = b2.x; R[cc][v][6] = b2.y; R[cc][v][7] = b2.z; R[cc][v][8] = b2.w;
        R[cc][v][0] = (col > 0) ? rowp[-1] : 0.0f;
        R[cc][v][9] = (col + 8 < HX) ? rowp[8] : 0.0f;
      }
    }
    if (top) {
#pragma unroll
      for (int cc = 0; cc < 4; cc++)
#pragma unroll
        for (int k = 0; k < 10; k++) R[cc][0][k] = 0.0f;
    }
    if (bot) {
#pragma unroll
      for (int cc = 0; cc < 4; cc++)
#pragma unroll
        for (int k = 0; k < 10; k++) R[cc][2][k] = 0.0f;
    }

#pragma unroll
    for (int pair = 0; pair < 2; pair++) {
      int ca = pair * 2, cb = ca + 1;
      const float* wa = wpos + (c0 + ca) * 9;
      const float* wb = wpos + (c0 + cb) * 9;
      float bva = bias[c0 + ca], bvb = bias[c0 + cb];
      float u0 = wa[0], u1 = wa[1], u2 = wa[2], u3 = wa[3], u4 = wa[4],
            u5 = wa[5], u6 = wa[6], u7 = wa[7], u8 = wa[8];
      float v0 = wb[0], v1 = wb[1], v2 = wb[2], v3 = wb[3], v4 = wb[4],
            v5 = wb[5], v6 = wb[6], v7 = wb[7], v8 = wb[8];
      int cs = csbase + pair * 2;      // uint32-aligned
#pragma unroll
      for (int k = 0; k < 8; k++) {
        float s = bva;
        s += u0 * R[ca][0][k]; s += u1 * R[ca][0][k + 1]; s += u2 * R[ca][0][k + 2];
        s += u3 * R[ca][1][k]; s += u4 * R[ca][1][k + 1]; s += u5 * R[ca][1][k + 2];
        s += u6 * R[ca][2][k]; s += u7 * R[ca][2][k + 1]; s += u8 * R[ca][2][k + 2];
        float oa = s + R[ca][1][k + 1];
        float t2 = bvb;
        t2 += v0 * R[cb][0][k]; t2 += v1 * R[cb][0][k + 1]; t2 += v2 * R[cb][0][k + 2];
        t2 += v3 * R[cb][1][k]; t2 += v4 * R[cb][1][k + 1]; t2 += v5 * R[cb][1][k + 2];
        t2 += v6 * R[cb][2][k]; t2 += v7 * R[cb][2][k + 1]; t2 += v8 * R[cb][2][k + 2];
        float ob = t2 + R[cb][1][k + 1];
        *(uint32_t*)&bufA[(pxg + k) * 136 + cs] = cvtpk(oa, ob);
      }
    }
  }
  __syncthreads();

  // ---- phase 2: MFMA 1x1 conv (v8 pipeline, unchanged) ----
  bf16x8 A[4];
  {
    int px = wave * 16 + l15;
    int swz = ((px >> 3) & 7) << 3;
#pragma unroll
    for (int kb = 0; kb < 4; kb++)
      A[kb] = __builtin_bit_cast(bf16x8,
          *(const uint4*)&bufA[px * 136 + ((kb * 32 + quad * 8) ^ swz)]);
  }

  const f32x4 zf = {0.f, 0.f, 0.f, 0.f};
  const uint4* wfu = (const uint4*)wf;
  uint4 Bc[4], Bn[4];
  {
    const uint4* fb = wfu + lane;  // tile 0
    Bc[0] = fb[0]; Bc[1] = fb[64]; Bc[2] = fb[128]; Bc[3] = fb[192];
  }
  int orow = wave * 16 + quad * 4;      // D-row base (px)
#pragma unroll 1
  for (int h = 0; h < 2; h++) {
#pragma unroll
    for (int tt = 0; tt < 8; tt++) {
      int t = h * 8 + tt;
      if (t < 15) {  // prefetch next tile's 4 B-fragments
        const uint4* fb = wfu + (size_t)(t + 1) * 256 + lane;
        Bn[0] = fb[0]; Bn[1] = fb[64]; Bn[2] = fb[128]; Bn[3] = fb[192];
      }
      f32x4 D = zf;
      D = __builtin_amdgcn_mfma_f32_16x16x32_bf16(A[0], __builtin_bit_cast(bf16x8, Bc[0]), D, 0, 0, 0);
      D = __builtin_amdgcn_mfma_f32_16x16x32_bf16(A[1], __builtin_bit_cast(bf16x8, Bc[1]), D, 0, 0, 0);
      D = __builtin_amdgcn_mfma_f32_16x16x32_bf16(A[2], __builtin_bit_cast(bf16x8, Bc[2]), D, 0, 0, 0);
      D = __builtin_amdgcn_mfma_f32_16x16x32_bf16(A[3], __builtin_bit_cast(bf16x8, Bc[3]), D, 0, 0, 0);
      int col = tt * 16 + l15;
#pragma unroll
      for (int r = 0; r < 4; r++) {
        int row = orow + r;
        bufA[row * 136 + (col ^ (((row >> 3) & 7) << 3))] = f2bf(D[r]);
      }
      if (t < 15) {
#pragma unroll
        for (int k = 0; k < 4; k++) Bc[k] = Bn[k];
      }
    }
    __syncthreads();
    {  // flush this o-half: 64 px x 128 o, coalesced
      int px = tid >> 2, og = (tid & 3) * 32;
      int swz = ((px >> 3) & 7) << 3;
      uint4* dstp = (uint4*)(y + ((size_t)b * HXW + p0 + px) * 256 + h * 128 + og);
#pragma unroll
      for (int j = 0; j < 4; j++)
        dstp[j] = *(const uint4*)&bufA[px * 136 + ((og + j * 8) ^ swz)];
    }
    __syncthreads();
  }
}

// ---------------------------------------------------------------------------
// Fused depthwise 3x3 K/V from bf16 NHWC tkv — v4: 2-channel lanes, 512-thr
// blocks, fused row-pair column streaming. Grid (496, 2), block 512.
// ---------------------------------------------------------------------------
template <bool VT, bool VB>
static __device__ __forceinline__ void dwkv_rowpair(
    const unsigned short* __restrict__ rm1, const unsigned short* __restrict__ r0,
    const unsigned short* __restrict__ r1, const unsigned short* __restrict__ r2,
    const f32x2 (&wp)[9], int px0, f32x2 (&a0)[8], f32x2 (&a1)[8]) {
  const f32x2 z2 = {0.f, 0.f};
#pragma unroll
  for (int p = 0; p < 8; p++) { a0[p] = z2; a1[p] = z2; }
#pragma unroll
  for (int j = 0; j < 10; j++) {
    int xcol = px0 - 1 + j;
    int xc = xcol;
    if (j == 0) xc = (xcol < 0) ? 0 : xcol;
    if (j == 9) xc = (xcol > HX - 1) ? HX - 1 : xcol;
    size_t off = (size_t)xc * 256;
    uint32_t um1 = 0, u0, u1, u2 = 0;
    u0 = *(const uint32_t*)(r0 + off);
    u1 = *(const uint32_t*)(r1 + off);
    if constexpr (VT) um1 = *(const uint32_t*)(rm1 + off);
    if constexpr (VB) u2 = *(const uint32_t*)(r2 + off);
    if (j == 0 || j == 9) {  // only edge columns can be out of range
      bool oob = (j == 0) ? (xcol < 0) : (xcol > HX - 1);
      if (oob) { um1 = 0u; u0 = 0u; u1 = 0u; u2 = 0u; }
    }
    f32x2 dm1, d0 = unp(u0), d1 = unp(u1), d2;
    if constexpr (VT) dm1 = unp(um1);
    if constexpr (VB) d2 = unp(u2);
    if (j <= 7) {
      if constexpr (VT) pkfma(a0[j], wp[0], dm1);
      pkfma(a0[j], wp[3], d0);
      pkfma(a0[j], wp[6], d1);
      pkfma(a1[j], wp[0], d0);
      pkfma(a1[j], wp[3], d1);
      if constexpr (VB) pkfma(a1[j], wp[6], d2);
    }
    if (j >= 1 && j <= 8) {
      if constexpr (VT) pkfma(a0[j - 1], wp[1], dm1);
      pkfma(a0[j - 1], wp[4], d0);
      pkfma(a0[j - 1], wp[7], d1);
      pkfma(a1[j - 1], wp[1], d0);
      pkfma(a1[j - 1], wp[4], d1);
      if constexpr (VB) pkfma(a1[j - 1], wp[7], d2);
    }
    if (j >= 2) {
      if constexpr (VT) pkfma(a0[j - 2], wp[2], dm1);
      pkfma(a0[j - 2], wp[5], d0);
      pkfma(a0[j - 2], wp[8], d1);
      pkfma(a1[j - 2], wp[2], d0);
      pkfma(a1[j - 2], wp[5], d1);
      if constexpr (VB) pkfma(a1[j - 2], wp[8], d2);
    }
  }
}

#define VTS 72                    // vt channel stride (shorts): 144 B, 16-B aligned
#define VTROW (128 * VTS + 16)    // vt row stride (shorts), +16 shifts banks

__global__ __launch_bounds__(512) __attribute__((amdgpu_waves_per_eu(4)))
void dwconv_kv_kernel(const unsigned short* __restrict__ tkv,
                      const float* __restrict__ w,
                      unsigned short* __restrict__ kT,
                      unsigned short* __restrict__ vv) {
  int fid = blockIdx.x;
  int xcd = fid & 7, slot = fid >> 3;
  int gi = xcd * 62 + slot;          // 0..495
  int strip = gi / 124;              // 0..3
  int g = gi % 124;                  // row-pair index
  int b = blockIdx.y;
  int x0 = strip * 64;
  int tid = threadIdx.x;
  int cl = tid & 127;                // channel lane: ch = 2*cl, 2*cl+1
  int pg = tid >> 7;                 // 0..3 px-group (wave-pair uniform)
  int ch0 = cl * 2;
  int hy0 = g * 2;

  f32x2 wp[9];
#pragma unroll
  for (int t = 0; t < 9; t++) {
    wp[t].x = w[ch0 * 9 + t];
    wp[t].y = w[(ch0 + 1) * 9 + t];
  }

  __shared__ __align__(16) unsigned short vt[2 * VTROW];  // 36,928 B

  const unsigned short* r0 = tkv + (size_t)b * HXW * 256 + (size_t)hy0 * (HX * 256) + ch0;
  const unsigned short* r1 = r0 + HX * 256;
  const unsigned short* rm1 = r0 - HX * 256;   // deref only when VT
  const unsigned short* r2 = r1 + HX * 256;    // deref only when VB
  bool isK = (cl < 64);
  int c0 = ch0 - 128;                // V-lane channel base

#pragma unroll 1
  for (int half = 0; half < 2; half++) {
    int px0 = x0 + pg * 16 + half * 8;
    if (px0 < HX) {  // strip 3 / pg 3 / half 1 is pure pad: skip
      f32x2 a0[8], a1[8];
      if (g == 0)        dwkv_rowpair<false, true >(rm1, r0, r1, r2, wp, px0, a0, a1);
      else if (g == 123) dwkv_rowpair<true,  false>(rm1, r0, r1, r2, wp, px0, a0, a1);
      else               dwkv_rowpair<true,  true >(rm1, r0, r1, r2, wp, px0, a0, a1);

      if (isK) {  // K rows: direct NHWC store, 2 ch packed per dword
        unsigned short* kb0 = kT + ((size_t)b * HXW + (size_t)hy0 * HX + px0) * 128 + ch0;
        unsigned short* kb1 = kb0 + (size_t)HX * 128;
#pragma unroll
        for (int p = 0; p < 8; p++) {
          *(uint32_t*)(kb0 + (size_t)p * 128) = cvtpk(a0[p].x, a0[p].y);
          *(uint32_t*)(kb1 + (size_t)p * 128) = cvtpk(a1[p].x, a1[p].y);
        }
      } else {    // V rows: stage transposed [row][ch][px] into LDS
        int pxr = pg * 16 + half * 8;
        unsigned short* v0 = vt + c0 * VTS + pxr;        // ch c0, row 0
        unsigned short* v1 = v0 + VTS;                   // ch c0+1
        uint2 d;
        d.x = cvtpk(a0[0].x, a0[1].x); d.y = cvtpk(a0[2].x, a0[3].x);
        *(uint2*)(v0) = d;
        d.x = cvtpk(a0[4].x, a0[5].x); d.y = cvtpk(a0[6].x, a0[7].x);
        *(uint2*)(v0 + 4) = d;
        d.x = cvtpk(a0[0].y, a0[1].y); d.y = cvtpk(a0[2].y, a0[3].y);
        *(uint2*)(v1) = d;
        d.x = cvtpk(a0[4].y, a0[5].y); d.y = cvtpk(a0[6].y, a0[7].y);
        *(uint2*)(v1 + 4) = d;
        d.x = cvtpk(a1[0].x, a1[1].x); d.y = cvtpk(a1[2].x, a1[3].x);
        *(uint2*)(v0 + VTROW) = d;
        d.x = cvtpk(a1[4].x, a1[5].x); d.y = cvtpk(a1[6].x, a1[7].x);
        *(uint2*)(v0 + VTROW + 4) = d;
        d.x = cvtpk(a1[0].y, a1[1].y); d.y = cvtpk(a1[2].y, a1[3].y);
        *(uint2*)(v1 + VTROW) = d;
        d.x = cvtpk(a1[4].y, a1[5].y); d.y = cvtpk(a1[6].y, a1[7].y);
        *(uint2*)(v1 + VTROW + 4) = d;
      }
    }
  }
  __syncthreads();
  {  // cooperative NCHW store of both V rows (full 128-B lines, padded rows)
    int ch = tid >> 2;
    int row = (tid >> 1) & 1;
    int ph = (tid & 1) * 32;
    const unsigned short* srcv = vt + row * VTROW + ch * VTS + ph;
    unsigned short* dst = vv + (size_t)(b * 128 + ch) * HXWP + (size_t)(hy0 + row) * HXP + x0 + ph;
#pragma unroll
    for (int j = 0; j < 4; j++)
      *(uint4*)(dst + j * 8) = *(const uint4*)(srcv + j * 8);
  }
}

// ---------------------------------------------------------------------------
// 1x1 conv tiled SGEMM (fp32) — small tensors (q path, output projection).
// ---------------------------------------------------------------------------
template <int O>
__global__ __launch_bounds__(256) void conv1_kernel(const float* __restrict__ x,
                                                    const float* __restrict__ w,
                                                    float* __restrict__ y, int HW) {
  constexpr int K = 128;
  constexpr int BK = 32;
  __shared__ __align__(16) float ws_s[BK][64];
  __shared__ __align__(16) float xs_s[BK][64];
  int b = blockIdx.z;
  int o0 = blockIdx.y * 64;
  int p0 = blockIdx.x * 64;
  const float* xb = x + (size_t)b * K * HW;
  int tx = threadIdx.x & 15;
  int ty = threadIdx.x >> 4;
  float acc[4][4] = {};
  int lo = threadIdx.x >> 2;
  int lk = (threadIdx.x & 3) * 8;
  int lc = threadIdx.x >> 3;
  int lp = (threadIdx.x & 7) * 8;

  for (int k0 = 0; k0 < K; k0 += BK) {
    __syncthreads();
    {
      const float* wp = w + (size_t)(o0 + lo) * K + k0 + lk;
      float4 a = *(const float4*)wp;
      float4 bq = *(const float4*)(wp + 4);
      ws_s[lk + 0][lo] = a.x;  ws_s[lk + 1][lo] = a.y;
      ws_s[lk + 2][lo] = a.z;  ws_s[lk + 3][lo] = a.w;
      ws_s[lk + 4][lo] = bq.x; ws_s[lk + 5][lo] = bq.y;
      ws_s[lk + 6][lo] = bq.z; ws_s[lk + 7][lo] = bq.w;
    }
    {
      int p = p0 + lp;
      const float* xp = xb + (size_t)(k0 + lc) * HW;
      float4 a, bq;
      if (p + 7 < HW) {
        a = *(const float4*)(xp + p);
        bq = *(const float4*)(xp + p + 4);
      } else {
        float tv[8];
#pragma unroll
        for (int j = 0; j < 8; j++) tv[j] = (p + j < HW) ? xp[p + j] : 0.0f;
        a = make_float4(tv[0], tv[1], tv[2], tv[3]);
        bq = make_float4(tv[4], tv[5], tv[6], tv[7]);
      }
      *(float4*)&xs_s[lc][lp] = a;
      *(float4*)&xs_s[lc][lp + 4] = bq;
    }
    __syncthreads();
#pragma unroll
    for (int k = 0; k < BK; k++) {
      float4 wv = *(const float4*)&ws_s[k][ty * 4];
      float4 xv = *(const float4*)&xs_s[k][tx * 4];
      acc[0][0] += wv.x * xv.x; acc[0][1] += wv.x * xv.y; acc[0][2] += wv.x * xv.z; acc[0][3] += wv.x * xv.w;
      acc[1][0] += wv.y * xv.x; acc[1][1] += wv.y * xv.y; acc[1][2] += wv.y * xv.z; acc[1][3] += wv.y * xv.w;
      acc[2][0] += wv.z * xv.x; acc[2][1] += wv.z * xv.y; acc[2][2] += wv.z * xv.z; acc[2][3] += wv.z * xv.w;
      acc[3][0] += wv.w * xv.x; acc[3][1] += wv.w * xv.y; acc[3][2] += wv.w * xv.z; acc[3][3] += wv.w * xv.w;
    }
  }
  int p = p0 + tx * 4;
  float* yb = y + (size_t)b * O * HW + (size_t)(o0 + ty * 4) * HW;
#pragma unroll
  for (int j = 0; j < 4; j++) {
    float* yr = yb + (size_t)j * HW + p;
    if (p + 3 < HW) {
      *(float4*)yr = make_float4(acc[j][0], acc[j][1], acc[j][2], acc[j][3]);
    } else {
#pragma unroll
      for (int e = 0; e < 4; e++) if (p + e < HW) yr[e] = acc[j][e];
    }
  }
}

// ---------------------------------------------------------------------------
// MFMA windowed attention v3 — one head per block. Grid 800 = (b,4h,100n),
// XCD-swizzled so each XCD owns one (b,h) slice x all windows. 256 thr =
// 4 oct-waves x 8 key rows. Single-pass epilogue, direct normalized output.
// ---------------------------------------------------------------------------
__global__ __launch_bounds__(256) void attn_mfma_kernel(
    const unsigned short* __restrict__ qn,   // (2,62,62,128) bf16, pre-scaled
    const unsigned short* __restrict__ kT,   // (2,248,248,128) bf16 NHWC
    const unsigned short* __restrict__ vp,   // (2,128,248,256p) bf16 NCHW padded
    float* __restrict__ o) {                 // (2,100,128,64)
  int fid = blockIdx.x;
  int xcd = fid & 7, slot = fid >> 3;        // slot 0..99
  int lin = xcd * 100 + slot;
  int n = lin % 100;
  int bh = lin / 100;                        // 0..7
  int h = bh & 3, b = bh >> 2;
  int wi = n / 10, wj = n % 10;
  int wave = threadIdx.x >> 6;               // oct 0..3
  int oct = wave;
  int lane = threadIdx.x & 63;
  int quad = lane >> 4;
  int l15 = lane & 15;
  int y0 = 24 * wi, x0 = 24 * wj;

  __shared__ __align__(16) unsigned short lds[16896];  // 33,792 B
  unsigned short* Pw = lds + wave * 2560;              // [q][40keys] 5KB/wave

  bf16x8 QB[4];
#pragma unroll
  for (int nt = 0; nt < 4; nt++) {
    int qq = nt * 16 + l15;
    int qy = 6 * wi + (qq >> 3), qx = 6 * wj + (qq & 7);
    QB[nt] = __builtin_bit_cast(bf16x8,
        *(const uint4*)(qn + ((size_t)(b * HSW + qy * HS + qx)) * 128 + h * 32 + quad * 8));
  }

  f32x4 Oacc[2][4];
#pragma unroll
  for (int a = 0; a < 2; a++)
#pragma unroll
    for (int c = 0; c < 4; c++) Oacc[a][c] = f32x4{0.f, 0.f, 0.f, 0.f};
  float lsum[4] = {0.f, 0.f, 0.f, 0.f};

  const unsigned short* kb = kT + (size_t)b * HXW * 128 + h * 32;
  const unsigned short* vb = vp + ((size_t)(b * 128 + h * 32)) * HXWP;
  const f32x4 zf = {0.f, 0.f, 0.f, 0.f};

#define LOADROW(r, K0, K1, V0, V1)                                              \
  {                                                                             \
    int y = y0 + (r);                                                           \
    const unsigned short* krow = kb + ((size_t)(y * HX + x0)) * 128;            \
    K0 = *(const uint4*)(krow + (size_t)l15 * 128 + quad * 8);                  \
    K1 = *(const uint4*)(krow + (size_t)(16 + l15) * 128 + quad * 8);           \
    const unsigned short* vrow = vb + (size_t)y * HXP + x0 + quad * 8;          \
    V0 = *(const uint4*)(vrow + (size_t)l15 * HXWP);                            \
    V1 = *(const uint4*)(vrow + (size_t)(16 + l15) * HXWP);                     \
  }

  auto compute = [&](uint4 k0, uint4 k1, uint4 v0, uint4 v1) {
    bf16x8 KA0 = __builtin_bit_cast(bf16x8, k0);
    bf16x8 KA1 = __builtin_bit_cast(bf16x8, k1);
    bf16x8 VA0 = __builtin_bit_cast(bf16x8, v0);
    bf16x8 VA1 = __builtin_bit_cast(bf16x8, v1);
    f32x4 S[2][4];
#pragma unroll
    for (int nt = 0; nt < 4; nt++) {
      S[0][nt] = __builtin_amdgcn_mfma_f32_16x16x32_bf16(KA0, QB[nt], zf, 0, 0, 0);
      S[1][nt] = __builtin_amdgcn_mfma_f32_16x16x32_bf16(KA1, QB[nt], zf, 0, 0, 0);
    }
#pragma unroll
    for (int nt = 0; nt < 4; nt++) {
      float pv[2][4];
      float cs = 0.f;
#pragma unroll
      for (int mt = 0; mt < 2; mt++)
#pragma unroll
        for (int r = 0; r < 4; r++) {
          pv[mt][r] = __expf(S[mt][nt][r]);
          cs += pv[mt][r];
        }
      lsum[nt] += cs;
#pragma unroll
      for (int mt = 0; mt < 2; mt++) {
        uint2 d;
        d.x = (uint32_t)f2bf(pv[mt][0]) | ((uint32_t)f2bf(pv[mt][1]) << 16);
        d.y = (uint32_t)f2bf(pv[mt][2]) | ((uint32_t)f2bf(pv[mt][3]) << 16);
        *(uint2*)(Pw + (16 * nt + l15) * 40 + 16 * mt + quad * 4) = d;
      }
    }
#pragma unroll
    for (int nt = 0; nt < 4; nt++) {
      bf16x8 PB = __builtin_bit_cast(bf16x8, *(const uint4*)(Pw + (16 * nt + l15) * 40 + quad * 8));
      Oacc[0][nt] = __builtin_amdgcn_mfma_f32_16x16x32_bf16(VA0, PB, Oacc[0][nt], 0, 0, 0);
      Oacc[1][nt] = __builtin_amdgcn_mfma_f32_16x16x32_bf16(VA1, PB, Oacc[1][nt], 0, 0, 0);
    }
  };

  int rbase = oct * 8;
  uint4 kA0, kA1, vA0, vA1, kB0, kB1, vB0, vB1;
  LOADROW(rbase + 0, kA0, kA1, vA0, vA1);
  LOADROW(rbase + 1, kB0, kB1, vB0, vB1);
#pragma unroll 1
  for (int r = 0; r < 8; r += 2) {
    compute(kA0, kA1, vA0, vA1);
    {
      int rn = (r + 2 < 8) ? (r + 2) : 6;  // clamped, branch-free
      LOADROW(rbase + rn, kA0, kA1, vA0, vA1);
    }
    compute(kB0, kB1, vB0, vB1);
    {
      int rn = (r + 3 < 8) ? (r + 3) : 7;  // clamped, branch-free
      LOADROW(rbase + rn, kB0, kB1, vB0, vB1);
    }
  }
#undef LOADROW

#pragma unroll
  for (int nt = 0; nt < 4; nt++) {
    lsum[nt] += __shfl_xor(lsum[nt], 16, 64);
    lsum[nt] += __shfl_xor(lsum[nt], 32, 64);
  }

  float* mO = (float*)lds;                 // [oct][32ch][64q]  32 KB
  float* mL = (float*)(lds + 16384);       // [oct][64q]  1 KB
  __syncthreads();  // all Pw reads done before overwrite
#pragma unroll
  for (int mt = 0; mt < 2; mt++)
#pragma unroll
    for (int nt = 0; nt < 4; nt++)
#pragma unroll
      for (int r = 0; r < 4; r++)
        mO[oct * 2048 + (16 * mt + quad * 4 + r) * 64 + 16 * nt + l15] = Oacc[mt][nt][r];
  if (quad == 0) {
#pragma unroll
    for (int nt = 0; nt < 4; nt++) mL[oct * 64 + nt * 16 + l15] = lsum[nt];
  }
  __syncthreads();
  {
    int q = threadIdx.x & 63;
    int cg = threadIdx.x >> 6;  // 0..3 -> 8 ch each
    float inv = 1.0f / (mL[q] + mL[64 + q] + mL[128 + q] + mL[192 + q]);
    float* ob = o + (((size_t)(b * 100 + n)) * 128 + h * 32 + cg * 8) * 64 + q;
#pragma unroll
    for (int e = 0; e < 8; e++) {
      int ch = cg * 8 + e;
      float s = mO[ch * 64 + q] + mO[2048 + ch * 64 + q] +
                mO[4096 + ch * 64 + q] + mO[6144 + ch * 64 + q];
      ob[(size_t)e * 64] = s * inv;
    }
  }
}

// ---------------------------------------------------------------------------
// Reverse: scatter-average overlapping 8x8 windows (step 6) into (2,128,62,62)
// ---------------------------------------------------------------------------
__global__ void reverse_kernel(const float* __restrict__ win, float* __restrict__ out) {
  int i = blockIdx.x * 256 + threadIdx.x;
  const int total = 2 * 128 * HSW;
  if (i >= total) return;
  int x = i % HS;
  int t = i / HS;
  int y = t % HS;
  t /= HS;
  int c = t % 128;
  int b = t / 128;
  int wi0 = (y >= 7) ? (y - 2) / 6 : 0;
  int wi1 = min(9, y / 6);
  int wj0 = (x >= 7) ? (x - 2) / 6 : 0;
  int wj1 = min(9, x / 6);
  float s = 0.0f;
  for (int wi = wi0; wi <= wi1; wi++)
    for (int wj = wj0; wj <= wj1; wj++) {
      int di = y - 6 * wi, dj = x - 6 * wj;
      s += win[(((size_t)(b * 100 + wi * 10 + wj)) * 128 + c) * 64 + di * 8 + dj];
    }
  float cnt = (float)((wi1 - wi0 + 1) * (wj1 - wj0 + 1));
  out[i] = s / cnt;
}

// ---------------------------------------------------------------------------
extern "C" void kernel_launch(void* const* d_in, const int* in_sizes, int n_in,
                              void* d_out, int out_size, void* d_ws, size_t ws_size,
                              hipStream_t stream) {
  const float* x      = (const float*)d_in[0];
  const float* sp     = (const float*)d_in[1];
  const float* w_pos  = (const float*)d_in[2];
  const float* b_pos  = (const float*)d_in[3];
  const float* w_q    = (const float*)d_in[4];
  const float* w_qdw  = (const float*)d_in[5];
  const float* w_kv   = (const float*)d_in[6];
  const float* w_kvdw = (const float*)d_in[7];
  const float* w_out  = (const float*)d_in[8];
  float* out = (float*)d_out;

  const size_t N_x   = (size_t)2 * 128 * HXW;   // 15,745,024 (shorts for kT)
  const size_t N_vp  = (size_t)2 * 128 * HXWP;  // 16,252,928 (padded vv, shorts)
  const size_t N_s   = (size_t)2 * 128 * HSW;
  const size_t N_att = (size_t)2 * 100 * 128 * 64;

  float* ws = (float*)d_ws;
  // shorts-based layout (all counts even -> float-aligned):
  unsigned short* kT  = (unsigned short*)ws;          // N_x shorts
  unsigned short* vv  = kT + N_x;                     // N_vp shorts (padded rows)
  unsigned short* tkv = vv + N_vp;                    // 2*N_x shorts
  float* att = (float*)tkv;                           // reuse (tkv dead after step 6)
  float* rev = att + N_att;
  float* spp = (float*)(tkv + 2 * N_x);
  float* tq  = spp + N_s;
  unsigned short* qn  = (unsigned short*)(tq + N_s);  // N_s shorts
  unsigned short* wkb = qn + N_s;                     // 32768 shorts (frag-packed)
  (void)ws_size; (void)in_sizes; (void)n_in; (void)out_size;

  // 0. wkb = bf16 fragment-packed w_kv
  pack_wfrag_kernel<<<16, 256, 0, stream>>>(w_kv, wkb);
  // 1+5 fused: tkv = bf16_nhwc(conv1(bf16(x + dwconv3(x)), wkb))
  {
    dim3 grid(961, 2);
    dwconv1_fused_kernel<<<grid, 256, 0, stream>>>(x, w_pos, b_pos, wkb, tkv);
  }
  // 2. spp = sp + dwconv3(sp, w_pos, b_pos)
  {
    int total = (int)N_s;
    dwconv3_kernel<<<(total + 255) / 256, 256, 0, stream>>>(sp, w_pos, b_pos, spp, 128, HS, HS, total, 1);
  }
  // 3. tq = conv1(spp, w_q)
  {
    int HW = HSW;
    dim3 grid((HW + 63) / 64, 2, 2);
    conv1_kernel<128><<<grid, 256, 0, stream>>>(spp, w_q, tq, HW);
  }
  // 4. qn = bf16_nhwc(dwconv3(tq, w_qdw)) * 32^-0.5
  {
    int total = (int)N_s;
    dwconv_q_kernel<<<(total + 255) / 256, 256, 0, stream>>>(tq, w_qdw, qn, total);
  }
  // 6. kT (NHWC) + vv (NCHW padded) = bf16(dwconv3(tkv, w_kvdw))
  {
    dim3 grid(496, 2);
    dwconv_kv_kernel<<<grid, 512, 0, stream>>>(tkv, w_kvdw, kT, vv);
  }
  // 7. attention -> att (2,100,128,64)   (800 one-head blocks, XCD-swizzled)
  {
    attn_mfma_kernel<<<800, 256, 0, stream>>>(qn, kT, vv, att);
  }
  // 8. rev = reverse(att)
  {
    int total = (int)N_s;
    reverse_kernel<<<(total + 255) / 256, 256, 0, stream>>>(att, rev);
  }
  // 9. out = conv1(rev, w_out)
  {
    int HW = HSW;
    dim3 grid((HW + 63) / 64, 2, 2);
    conv1_kernel<128><<<grid, 256, 0, stream>>>(rev, w_out, out, HW);
  }
}

// Round 11
// 257.233 us; speedup vs baseline: 1.0387x; 1.0376x over previous
//
#include <hip/hip_runtime.h>
#include <cstdint>

#define HS 62
#define HX 248
#define HXW (HX * HX)  // 61504
#define HSW (HS * HS)  // 3844
#define HXP 256        // padded row stride for vv (128-B aligned rows)
#define HXWP (HX * HXP)  // 63488 padded plane

typedef __attribute__((ext_vector_type(8))) short bf16x8;
typedef __attribute__((ext_vector_type(4))) float f32x4;
typedef __attribute__((ext_vector_type(2))) float f32x2;

static __device__ __forceinline__ unsigned short f2bf(float f) {
  uint32_t u = __builtin_bit_cast(uint32_t, f);
  u += 0x7fff + ((u >> 16) & 1);  // RNE
  return (unsigned short)(u >> 16);
}
static __device__ __forceinline__ float bf2f(unsigned short u) {
  uint32_t x = (uint32_t)u << 16;
  return __builtin_bit_cast(float, x);
}
static __device__ __forceinline__ float bflo(uint32_t u) {
  return __builtin_bit_cast(float, u << 16);
}
static __device__ __forceinline__ float bfhi(uint32_t u) {
  return __builtin_bit_cast(float, u & 0xffff0000u);
}

// packed fp32 FMA: acc = a*b + acc (2 lanes of fp32, CDNA v_pk_fma_f32)
static __device__ __forceinline__ void pkfma(f32x2& acc, f32x2 a, f32x2 b) {
  asm("v_pk_fma_f32 %0, %1, %2, %0" : "+v"(acc) : "v"(a), "v"(b));
}
// packed f32->bf16 RNE convert: returns (bf16(lo) | bf16(hi)<<16)
static __device__ __forceinline__ uint32_t cvtpk(float lo, float hi) {
  uint32_t r;
  asm("v_cvt_pk_bf16_f32 %0, %1, %2" : "=v"(r) : "v"(lo), "v"(hi));
  return r;
}
// unpack u32 holding 2 bf16 -> packed f32 pair
static __device__ __forceinline__ f32x2 unp(uint32_t u) {
  f32x2 r;
  r.x = __builtin_bit_cast(float, u << 16);
  r.y = __builtin_bit_cast(float, u & 0xffff0000u);
  return r;
}

// ---------------------------------------------------------------------------
// Depthwise 3x3 scalar (62x62 tensors), fp32 out, bias+residual.
// ---------------------------------------------------------------------------
__global__ void dwconv3_kernel(const float* __restrict__ x, const float* __restrict__ w,
                               const float* __restrict__ bias, float* __restrict__ y,
                               int C, int H, int W, int total, int residual) {
  int i = blockIdx.x * 256 + threadIdx.x;
  if (i >= total) return;
  int wx = i % W;
  int t = i / W;
  int hy = t % H;
  int bc = t / H;
  int c = bc % C;
  const float* xb = x + (size_t)bc * H * W;
  const float* wc = w + c * 9;
  float s = bias ? bias[c] : 0.0f;
  for (int di = -1; di <= 1; di++) {
    int h2 = hy + di;
    if (h2 < 0 || h2 >= H) continue;
    for (int dj = -1; dj <= 1; dj++) {
      int w2 = wx + dj;
      if (w2 < 0 || w2 >= W) continue;
      s += xb[(size_t)h2 * W + w2] * wc[(di + 1) * 3 + (dj + 1)];
    }
  }
  if (residual) s += xb[(size_t)hy * W + wx];
  y[i] = s;
}

// ---------------------------------------------------------------------------
// Depthwise 3x3 x-path v2: fp32 NCHW in -> bf16 NCHW out, residual.
// 8 px x 2 rows per thread.
// ---------------------------------------------------------------------------
__global__ __launch_bounds__(256) void dwconv8x2_bf16_kernel(
    const float* __restrict__ x, const float* __restrict__ w,
    const float* __restrict__ bias, unsigned short* __restrict__ y, int total) {
  int i = blockIdx.x * 256 + threadIdx.x;
  if (i >= total) return;
  int wq = (i % 31) * 8;
  int t = i / 31;
  int hp = t % 124;
  int bc = t / 124;
  int c = bc & 127;
  int hy = hp * 2;
  const float* xb = x + (size_t)bc * HXW;
  const float* wc = w + c * 9;
  float bv = bias[c];

  float rm1[10], r0[10], r1[10], r2[10];
  auto loadrow = [&](int h2, float (&r)[10]) {
    const float* row = xb + (size_t)h2 * HX + wq;
    float4 a = *(const float4*)row;
    float4 b2 = *(const float4*)(row + 4);
    r[1] = a.x;  r[2] = a.y;  r[3] = a.z;  r[4] = a.w;
    r[5] = b2.x; r[6] = b2.y; r[7] = b2.z; r[8] = b2.w;
    r[0] = (wq > 0) ? row[-1] : 0.0f;
    r[9] = (wq + 8 < HX) ? row[8] : 0.0f;
  };
  loadrow((hy > 0) ? hy - 1 : 0, rm1);
  loadrow(hy, r0);
  loadrow(hy + 1, r1);
  loadrow((hy + 2 < HX) ? hy + 2 : HX - 1, r2);
  if (hp == 0) {
#pragma unroll
    for (int k = 0; k < 10; k++) rm1[k] = 0.0f;
  }
  if (hp == 123) {
#pragma unroll
    for (int k = 0; k < 10; k++) r2[k] = 0.0f;
  }

  float w0 = wc[0], w1 = wc[1], w2 = wc[2];
  float w3 = wc[3], w4 = wc[4], w5 = wc[5];
  float w6 = wc[6], w7 = wc[7], w8 = wc[8];

  float o0[8], o1[8];
#pragma unroll
  for (int k = 0; k < 8; k++) {
    float s = bv;
    s += w0 * rm1[k]; s += w1 * rm1[k + 1]; s += w2 * rm1[k + 2];
    s += w3 * r0[k];  s += w4 * r0[k + 1];  s += w5 * r0[k + 2];
    s += w6 * r1[k];  s += w7 * r1[k + 1];  s += w8 * r1[k + 2];
    o0[k] = s + r0[k + 1];
    float u = bv;
    u += w0 * r0[k]; u += w1 * r0[k + 1]; u += w2 * r0[k + 2];
    u += w3 * r1[k]; u += w4 * r1[k + 1]; u += w5 * r1[k + 2];
    u += w6 * r2[k]; u += w7 * r2[k + 1]; u += w8 * r2[k + 2];
    o1[k] = u + r1[k + 1];
  }
  uint4 d0, d1;
  d0.x = cvtpk(o0[0], o0[1]); d0.y = cvtpk(o0[2], o0[3]);
  d0.z = cvtpk(o0[4], o0[5]); d0.w = cvtpk(o0[6], o0[7]);
  d1.x = cvtpk(o1[0], o1[1]); d1.y = cvtpk(o1[2], o1[3]);
  d1.z = cvtpk(o1[4], o1[5]); d1.w = cvtpk(o1[6], o1[7]);
  unsigned short* yb = y + (size_t)bc * HXW + (size_t)hy * HX + wq;
  *(uint4*)yb = d0;
  *(uint4*)(yb + HX) = d1;
}

// ---------------------------------------------------------------------------
// fp32 -> bf16 flat convert (for w_kv).
// ---------------------------------------------------------------------------
__global__ void cvt_bf16_kernel(const float* __restrict__ src, unsigned short* __restrict__ dst,
                                int n) {
  int i = blockIdx.x * 256 + threadIdx.x;
  if (i < n) dst[i] = f2bf(src[i]);
}

// ---------------------------------------------------------------------------
// Depthwise 3x3 q path: fp32 NCHW in -> bf16 NHWC out, pre-scaled by 32^-0.5.
// ---------------------------------------------------------------------------
__global__ void dwconv_q_kernel(const float* __restrict__ x, const float* __restrict__ w,
                                unsigned short* __restrict__ qn, int total) {
  int i = blockIdx.x * 256 + threadIdx.x;
  if (i >= total) return;
  int wx = i % HS;
  int t = i / HS;
  int hy = t % HS;
  int bc = t / HS;
  int c = bc & 127;
  int b = bc >> 7;
  const float* xb = x + (size_t)bc * HSW;
  const float* wc = w + c * 9;
  float s = 0.0f;
  for (int di = -1; di <= 1; di++) {
    int h2 = hy + di;
    if (h2 < 0 || h2 >= HS) continue;
    for (int dj = -1; dj <= 1; dj++) {
      int w2 = wx + dj;
      if (w2 < 0 || w2 >= HS) continue;
      s += xb[(size_t)h2 * HS + w2] * wc[(di + 1) * 3 + (dj + 1)];
    }
  }
  qn[((size_t)(b * HSW + hy * HS + wx)) * 128 + c] = f2bf(s * 0.17677669529663688f);
}

// ---------------------------------------------------------------------------
// MFMA 1x1 conv kv path, v3: weights staged in LDS per 64-o quarter.
// Block = 64 px x 256 o, 4 waves. Grid (961, 2).
// ---------------------------------------------------------------------------
__global__ __launch_bounds__(256) void conv1_kv_mfma_kernel(
    const unsigned short* __restrict__ xpb,  // (2,128,61504) bf16 NCHW
    const unsigned short* __restrict__ wkb,  // (256,128) bf16
    unsigned short* __restrict__ y) {        // (2,61504,256) bf16 NHWC
  int b = blockIdx.y;
  int p0 = blockIdx.x * 64;
  int tid = threadIdx.x;
  int wave = tid >> 6, lane = tid & 63, quad = lane >> 4, l15 = lane & 15;
  __shared__ __align__(16) unsigned short bufA[64 * 136];  // 17,408 B
  __shared__ __align__(16) unsigned short bufW[64 * 136];  // 17,408 B

  // phase 1: stage X-tile as bufA[px][c], stride 136
  {
    int c = tid >> 1, half = tid & 1;
    const unsigned short* src = xpb + ((size_t)(b * 128 + c)) * HXW + p0 + half * 32;
#pragma unroll
    for (int j = 0; j < 8; j++) {
      uint2 v = *(const uint2*)(src + j * 4);
      int px = half * 32 + j * 4;
      bufA[(px + 0) * 136 + c] = (unsigned short)(v.x & 0xffff);
      bufA[(px + 1) * 136 + c] = (unsigned short)(v.x >> 16);
      bufA[(px + 2) * 136 + c] = (unsigned short)(v.y & 0xffff);
      bufA[(px + 3) * 136 + c] = (unsigned short)(v.y >> 16);
    }
  }
  __syncthreads();
  bf16x8 A[4];
#pragma unroll
  for (int kb = 0; kb < 4; kb++)
    A[kb] = __builtin_bit_cast(bf16x8,
        *(const uint4*)&bufA[(wave * 16 + l15) * 136 + kb * 32 + quad * 8]);
  // bufA becomes the output stage after the next barrier.

  const f32x4 zf = {0.f, 0.f, 0.f, 0.f};
#pragma unroll 1
  for (int h = 0; h < 2; h++) {
#pragma unroll 1
    for (int oq = 0; oq < 2; oq++) {
      __syncthreads();  // bufW reusable; (h>0: bufA flush complete)
      {  // cooperative coalesced load of one 64-o weight quarter -> bufW
        int orow = tid >> 2;          // 0..63
        int cseg = (tid & 3) * 32;    // 0,32,64,96
        const unsigned short* src = wkb + (size_t)(h * 128 + oq * 64 + orow) * 128 + cseg;
        unsigned short* dst = &bufW[orow * 136 + cseg];
        *(uint4*)(dst)      = *(const uint4*)(src);
        *(uint4*)(dst + 8)  = *(const uint4*)(src + 8);
        *(uint4*)(dst + 16) = *(const uint4*)(src + 16);
        *(uint4*)(dst + 24) = *(const uint4*)(src + 24);
      }
      __syncthreads();
#pragma unroll
      for (int ot = 0; ot < 4; ot++) {
        const unsigned short* wrow = &bufW[(ot * 16 + l15) * 136 + quad * 8];
        f32x4 D = zf;
        D = __builtin_amdgcn_mfma_f32_16x16x32_bf16(A[0], __builtin_bit_cast(bf16x8, *(const uint4*)(wrow)),      D, 0, 0, 0);
        D = __builtin_amdgcn_mfma_f32_16x16x32_bf16(A[1], __builtin_bit_cast(bf16x8, *(const uint4*)(wrow + 32)), D, 0, 0, 0);
        D = __builtin_amdgcn_mfma_f32_16x16x32_bf16(A[2], __builtin_bit_cast(bf16x8, *(const uint4*)(wrow + 64)), D, 0, 0, 0);
        D = __builtin_amdgcn_mfma_f32_16x16x32_bf16(A[3], __builtin_bit_cast(bf16x8, *(const uint4*)(wrow + 96)), D, 0, 0, 0);
#pragma unroll
        for (int r = 0; r < 4; r++)
          bufA[(wave * 16 + quad * 4 + r) * 136 + (oq * 4 + ot) * 16 + l15] = f2bf(D[r]);
      }
    }
    __syncthreads();
    {  // flush this o-half: 64 px x 128 o, coalesced
      int px = tid >> 2, og = (tid & 3) * 32;
      const uint4* srcp = (const uint4*)&bufA[px * 136 + og];
      uint4* dstp = (uint4*)(y + ((size_t)b * HXW + p0 + px) * 256 + h * 128 + og);
#pragma unroll
      for (int j = 0; j < 4; j++) dstp[j] = srcp[j];
    }
  }
}

// ---------------------------------------------------------------------------
// Fused depthwise 3x3 K/V from bf16 NHWC tkv — v4: 2-channel lanes, 512-thr
// blocks, fused row-pair column streaming. Grid (496, 2), block 512.
// ---------------------------------------------------------------------------
template <bool VT, bool VB>
static __device__ __forceinline__ void dwkv_rowpair(
    const unsigned short* __restrict__ rm1, const unsigned short* __restrict__ r0,
    const unsigned short* __restrict__ r1, const unsigned short* __restrict__ r2,
    const f32x2 (&wp)[9], int px0, f32x2 (&a0)[8], f32x2 (&a1)[8]) {
  const f32x2 z2 = {0.f, 0.f};
#pragma unroll
  for (int p = 0; p < 8; p++) { a0[p] = z2; a1[p] = z2; }
#pragma unroll
  for (int j = 0; j < 10; j++) {
    int xcol = px0 - 1 + j;
    int xc = xcol;
    if (j == 0) xc = (xcol < 0) ? 0 : xcol;
    if (j == 9) xc = (xcol > HX - 1) ? HX - 1 : xcol;
    size_t off = (size_t)xc * 256;
    uint32_t um1 = 0, u0, u1, u2 = 0;
    u0 = *(const uint32_t*)(r0 + off);
    u1 = *(const uint32_t*)(r1 + off);
    if constexpr (VT) um1 = *(const uint32_t*)(rm1 + off);
    if constexpr (VB) u2 = *(const uint32_t*)(r2 + off);
    if (j == 0 || j == 9) {  // only edge columns can be out of range
      bool oob = (j == 0) ? (xcol < 0) : (xcol > HX - 1);
      if (oob) { um1 = 0u; u0 = 0u; u1 = 0u; u2 = 0u; }
    }
    f32x2 dm1, d0 = unp(u0), d1 = unp(u1), d2;
    if constexpr (VT) dm1 = unp(um1);
    if constexpr (VB) d2 = unp(u2);
    if (j <= 7) {
      if constexpr (VT) pkfma(a0[j], wp[0], dm1);
      pkfma(a0[j], wp[3], d0);
      pkfma(a0[j], wp[6], d1);
      pkfma(a1[j], wp[0], d0);
      pkfma(a1[j], wp[3], d1);
      if constexpr (VB) pkfma(a1[j], wp[6], d2);
    }
    if (j >= 1 && j <= 8) {
      if constexpr (VT) pkfma(a0[j - 1], wp[1], dm1);
      pkfma(a0[j - 1], wp[4], d0);
      pkfma(a0[j - 1], wp[7], d1);
      pkfma(a1[j - 1], wp[1], d0);
      pkfma(a1[j - 1], wp[4], d1);
      if constexpr (VB) pkfma(a1[j - 1], wp[7], d2);
    }
    if (j >= 2) {
      if constexpr (VT) pkfma(a0[j - 2], wp[2], dm1);
      pkfma(a0[j - 2], wp[5], d0);
      pkfma(a0[j - 2], wp[8], d1);
      pkfma(a1[j - 2], wp[2], d0);
      pkfma(a1[j - 2], wp[5], d1);
      if constexpr (VB) pkfma(a1[j - 2], wp[8], d2);
    }
  }
}

#define VTS 72                    // vt channel stride (shorts): 144 B, 16-B aligned
#define VTROW (128 * VTS + 16)    // vt row stride (shorts), +16 shifts banks

__global__ __launch_bounds__(512) __attribute__((amdgpu_waves_per_eu(4)))
void dwconv_kv_kernel(const unsigned short* __restrict__ tkv,
                      const float* __restrict__ w,
                      unsigned short* __restrict__ kT,
                      unsigned short* __restrict__ vv) {
  int fid = blockIdx.x;
  int xcd = fid & 7, slot = fid >> 3;
  int gi = xcd * 62 + slot;          // 0..495
  int strip = gi / 124;              // 0..3
  int g = gi % 124;                  // row-pair index
  int b = blockIdx.y;
  int x0 = strip * 64;
  int tid = threadIdx.x;
  int cl = tid & 127;                // channel lane: ch = 2*cl, 2*cl+1
  int pg = tid >> 7;                 // 0..3 px-group (wave-pair uniform)
  int ch0 = cl * 2;
  int hy0 = g * 2;

  f32x2 wp[9];
#pragma unroll
  for (int t = 0; t < 9; t++) {
    wp[t].x = w[ch0 * 9 + t];
    wp[t].y = w[(ch0 + 1) * 9 + t];
  }

  __shared__ __align__(16) unsigned short vt[2 * VTROW];  // 36,928 B

  const unsigned short* r0 = tkv + (size_t)b * HXW * 256 + (size_t)hy0 * (HX * 256) + ch0;
  const unsigned short* r1 = r0 + HX * 256;
  const unsigned short* rm1 = r0 - HX * 256;   // deref only when VT
  const unsigned short* r2 = r1 + HX * 256;    // deref only when VB
  bool isK = (cl < 64);
  int c0 = ch0 - 128;                // V-lane channel base

#pragma unroll 1
  for (int half = 0; half < 2; half++) {
    int px0 = x0 + pg * 16 + half * 8;
    if (px0 < HX) {  // strip 3 / pg 3 / half 1 is pure pad: skip
      f32x2 a0[8], a1[8];
      if (g == 0)        dwkv_rowpair<false, true >(rm1, r0, r1, r2, wp, px0, a0, a1);
      else if (g == 123) dwkv_rowpair<true,  false>(rm1, r0, r1, r2, wp, px0, a0, a1);
      else               dwkv_rowpair<true,  true >(rm1, r0, r1, r2, wp, px0, a0, a1);

      if (isK) {  // K rows: direct NHWC store, 2 ch packed per dword
        unsigned short* kb0 = kT + ((size_t)b * HXW + (size_t)hy0 * HX + px0) * 128 + ch0;
        unsigned short* kb1 = kb0 + (size_t)HX * 128;
#pragma unroll
        for (int p = 0; p < 8; p++) {
          *(uint32_t*)(kb0 + (size_t)p * 128) = cvtpk(a0[p].x, a0[p].y);
          *(uint32_t*)(kb1 + (size_t)p * 128) = cvtpk(a1[p].x, a1[p].y);
        }
      } else {    // V rows: stage transposed [row][ch][px] into LDS
        int pxr = pg * 16 + half * 8;
        unsigned short* v0 = vt + c0 * VTS + pxr;        // ch c0, row 0
        unsigned short* v1 = v0 + VTS;                   // ch c0+1
        uint2 d;
        d.x = cvtpk(a0[0].x, a0[1].x); d.y = cvtpk(a0[2].x, a0[3].x);
        *(uint2*)(v0) = d;
        d.x = cvtpk(a0[4].x, a0[5].x); d.y = cvtpk(a0[6].x, a0[7].x);
        *(uint2*)(v0 + 4) = d;
        d.x = cvtpk(a0[0].y, a0[1].y); d.y = cvtpk(a0[2].y, a0[3].y);
        *(uint2*)(v1) = d;
        d.x = cvtpk(a0[4].y, a0[5].y); d.y = cvtpk(a0[6].y, a0[7].y);
        *(uint2*)(v1 + 4) = d;
        d.x = cvtpk(a1[0].x, a1[1].x); d.y = cvtpk(a1[2].x, a1[3].x);
        *(uint2*)(v0 + VTROW) = d;
        d.x = cvtpk(a1[4].x, a1[5].x); d.y = cvtpk(a1[6].x, a1[7].x);
        *(uint2*)(v0 + VTROW + 4) = d;
        d.x = cvtpk(a1[0].y, a1[1].y); d.y = cvtpk(a1[2].y, a1[3].y);
        *(uint2*)(v1 + VTROW) = d;
        d.x = cvtpk(a1[4].y, a1[5].y); d.y = cvtpk(a1[6].y, a1[7].y);
        *(uint2*)(v1 + VTROW + 4) = d;
      }
    }
  }
  __syncthreads();
  {  // cooperative NCHW store of both V rows (full 128-B lines, padded rows)
    int ch = tid >> 2;
    int row = (tid >> 1) & 1;
    int ph = (tid & 1) * 32;
    const unsigned short* srcv = vt + row * VTROW + ch * VTS + ph;
    unsigned short* dst = vv + (size_t)(b * 128 + ch) * HXWP + (size_t)(hy0 + row) * HXP + x0 + ph;
#pragma unroll
    for (int j = 0; j < 4; j++)
      *(uint4*)(dst + j * 8) = *(const uint4*)(srcv + j * 8);
  }
}

// ---------------------------------------------------------------------------
// 1x1 conv tiled SGEMM (fp32) — small tensors (q path, output projection).
// ---------------------------------------------------------------------------
template <int O>
__global__ __launch_bounds__(256) void conv1_kernel(const float* __restrict__ x,
                                                    const float* __restrict__ w,
                                                    float* __restrict__ y, int HW) {
  constexpr int K = 128;
  constexpr int BK = 32;
  __shared__ __align__(16) float ws_s[BK][64];
  __shared__ __align__(16) float xs_s[BK][64];
  int b = blockIdx.z;
  int o0 = blockIdx.y * 64;
  int p0 = blockIdx.x * 64;
  const float* xb = x + (size_t)b * K * HW;
  int tx = threadIdx.x & 15;
  int ty = threadIdx.x >> 4;
  float acc[4][4] = {};
  int lo = threadIdx.x >> 2;
  int lk = (threadIdx.x & 3) * 8;
  int lc = threadIdx.x >> 3;
  int lp = (threadIdx.x & 7) * 8;

  for (int k0 = 0; k0 < K; k0 += BK) {
    __syncthreads();
    {
      const float* wp = w + (size_t)(o0 + lo) * K + k0 + lk;
      float4 a = *(const float4*)wp;
      float4 bq = *(const float4*)(wp + 4);
      ws_s[lk + 0][lo] = a.x;  ws_s[lk + 1][lo] = a.y;
      ws_s[lk + 2][lo] = a.z;  ws_s[lk + 3][lo] = a.w;
      ws_s[lk + 4][lo] = bq.x; ws_s[lk + 5][lo] = bq.y;
      ws_s[lk + 6][lo] = bq.z; ws_s[lk + 7][lo] = bq.w;
    }
    {
      int p = p0 + lp;
      const float* xp = xb + (size_t)(k0 + lc) * HW;
      float4 a, bq;
      if (p + 7 < HW) {
        a = *(const float4*)(xp + p);
        bq = *(const float4*)(xp + p + 4);
      } else {
        float tv[8];
#pragma unroll
        for (int j = 0; j < 8; j++) tv[j] = (p + j < HW) ? xp[p + j] : 0.0f;
        a = make_float4(tv[0], tv[1], tv[2], tv[3]);
        bq = make_float4(tv[4], tv[5], tv[6], tv[7]);
      }
      *(float4*)&xs_s[lc][lp] = a;
      *(float4*)&xs_s[lc][lp + 4] = bq;
    }
    __syncthreads();
#pragma unroll
    for (int k = 0; k < BK; k++) {
      float4 wv = *(const float4*)&ws_s[k][ty * 4];
      float4 xv = *(const float4*)&xs_s[k][tx * 4];
      acc[0][0] += wv.x * xv.x; acc[0][1] += wv.x * xv.y; acc[0][2] += wv.x * xv.z; acc[0][3] += wv.x * xv.w;
      acc[1][0] += wv.y * xv.x; acc[1][1] += wv.y * xv.y; acc[1][2] += wv.y * xv.z; acc[1][3] += wv.y * xv.w;
      acc[2][0] += wv.z * xv.x; acc[2][1] += wv.z * xv.y; acc[2][2] += wv.z * xv.z; acc[2][3] += wv.z * xv.w;
      acc[3][0] += wv.w * xv.x; acc[3][1] += wv.w * xv.y; acc[3][2] += wv.w * xv.z; acc[3][3] += wv.w * xv.w;
    }
  }
  int p = p0 + tx * 4;
  float* yb = y + (size_t)b * O * HW + (size_t)(o0 + ty * 4) * HW;
#pragma unroll
  for (int j = 0; j < 4; j++) {
    float* yr = yb + (size_t)j * HW + p;
    if (p + 3 < HW) {
      *(float4*)yr = make_float4(acc[j][0], acc[j][1], acc[j][2], acc[j][3]);
    } else {
#pragma unroll
      for (int e = 0; e < 4; e++) if (p + e < HW) yr[e] = acc[j][e];
    }
  }
}

// ---------------------------------------------------------------------------
// MFMA windowed attention v3 — one head per block. Grid 800 = (b,4h,100n),
// XCD-swizzled so each XCD owns one (b,h) slice x all windows. 256 thr =
// 4 oct-waves x 8 key rows. Single-pass epilogue, direct normalized output.
// ---------------------------------------------------------------------------
__global__ __launch_bounds__(256) void attn_mfma_kernel(
    const unsigned short* __restrict__ qn,   // (2,62,62,128) bf16, pre-scaled
    const unsigned short* __restrict__ kT,   // (2,248,248,128) bf16 NHWC
    const unsigned short* __restrict__ vp,   // (2,128,248,256p) bf16 NCHW padded
    float* __restrict__ o) {                 // (2,100,128,64)
  int fid = blockIdx.x;
  int xcd = fid & 7, slot = fid >> 3;        // slot 0..99
  int lin = xcd * 100 + slot;
  int n = lin % 100;
  int bh = lin / 100;                        // 0..7
  int h = bh & 3, b = bh >> 2;
  int wi = n / 10, wj = n % 10;
  int wave = threadIdx.x >> 6;               // oct 0..3
  int oct = wave;
  int lane = threadIdx.x & 63;
  int quad = lane >> 4;
  int l15 = lane & 15;
  int y0 = 24 * wi, x0 = 24 * wj;

  __shared__ __align__(16) unsigned short lds[16896];  // 33,792 B
  unsigned short* Pw = lds + wave * 2560;              // [q][40keys] 5KB/wave

  bf16x8 QB[4];
#pragma unroll
  for (int nt = 0; nt < 4; nt++) {
    int qq = nt * 16 + l15;
    int qy = 6 * wi + (qq >> 3), qx = 6 * wj + (qq & 7);
    QB[nt] = __builtin_bit_cast(bf16x8,
        *(const uint4*)(qn + ((size_t)(b * HSW + qy * HS + qx)) * 128 + h * 32 + quad * 8));
  }

  f32x4 Oacc[2][4];
#pragma unroll
  for (int a = 0; a < 2; a++)
#pragma unroll
    for (int c = 0; c < 4; c++) Oacc[a][c] = f32x4{0.f, 0.f, 0.f, 0.f};
  float lsum[4] = {0.f, 0.f, 0.f, 0.f};

  const unsigned short* kb = kT + (size_t)b * HXW * 128 + h * 32;
  const unsigned short* vb = vp + ((size_t)(b * 128 + h * 32)) * HXWP;
  const f32x4 zf = {0.f, 0.f, 0.f, 0.f};

#define LOADROW(r, K0, K1, V0, V1)                                              \
  {                                                                             \
    int y = y0 + (r);                                                           \
    const unsigned short* krow = kb + ((size_t)(y * HX + x0)) * 128;            \
    K0 = *(const uint4*)(krow + (size_t)l15 * 128 + quad * 8);                  \
    K1 = *(const uint4*)(krow + (size_t)(16 + l15) * 128 + quad * 8);           \
    const unsigned short* vrow = vb + (size_t)y * HXP + x0 + quad * 8;          \
    V0 = *(const uint4*)(vrow + (size_t)l15 * HXWP);                            \
    V1 = *(const uint4*)(vrow + (size_t)(16 + l15) * HXWP);                     \
  }

  auto compute = [&](uint4 k0, uint4 k1, uint4 v0, uint4 v1) {
    bf16x8 KA0 = __builtin_bit_cast(bf16x8, k0);
    bf16x8 KA1 = __builtin_bit_cast(bf16x8, k1);
    bf16x8 VA0 = __builtin_bit_cast(bf16x8, v0);
    bf16x8 VA1 = __builtin_bit_cast(bf16x8, v1);
    f32x4 S[2][4];
#pragma unroll
    for (int nt = 0; nt < 4; nt++) {
      S[0][nt] = __builtin_amdgcn_mfma_f32_16x16x32_bf16(KA0, QB[nt], zf, 0, 0, 0);
      S[1][nt] = __builtin_amdgcn_mfma_f32_16x16x32_bf16(KA1, QB[nt], zf, 0, 0, 0);
    }
#pragma unroll
    for (int nt = 0; nt < 4; nt++) {
      float pv[2][4];
      float cs = 0.f;
#pragma unroll
      for (int mt = 0; mt < 2; mt++)
#pragma unroll
        for (int r = 0; r < 4; r++) {
          pv[mt][r] = __expf(S[mt][nt][r]);
          cs += pv[mt][r];
        }
      lsum[nt] += cs;
#pragma unroll
      for (int mt = 0; mt < 2; mt++) {
        uint2 d;
        d.x = (uint32_t)f2bf(pv[mt][0]) | ((uint32_t)f2bf(pv[mt][1]) << 16);
        d.y = (uint32_t)f2bf(pv[mt][2]) | ((uint32_t)f2bf(pv[mt][3]) << 16);
        *(uint2*)(Pw + (16 * nt + l15) * 40 + 16 * mt + quad * 4) = d;
      }
    }
#pragma unroll
    for (int nt = 0; nt < 4; nt++) {
      bf16x8 PB = __builtin_bit_cast(bf16x8, *(const uint4*)(Pw + (16 * nt + l15) * 40 + quad * 8));
      Oacc[0][nt] = __builtin_amdgcn_mfma_f32_16x16x32_bf16(VA0, PB, Oacc[0][nt], 0, 0, 0);
      Oacc[1][nt] = __builtin_amdgcn_mfma_f32_16x16x32_bf16(VA1, PB, Oacc[1][nt], 0, 0, 0);
    }
  };

  int rbase = oct * 8;
  uint4 kA0, kA1, vA0, vA1, kB0, kB1, vB0, vB1;
  LOADROW(rbase + 0, kA0, kA1, vA0, vA1);
  LOADROW(rbase + 1, kB0, kB1, vB0, vB1);
#pragma unroll 1
  for (int r = 0; r < 8; r += 2) {
    compute(kA0, kA1, vA0, vA1);
    {
      int rn = (r + 2 < 8) ? (r + 2) : 6;  // clamped, branch-free
      LOADROW(rbase + rn, kA0, kA1, vA0, vA1);
    }
    compute(kB0, kB1, vB0, vB1);
    {
      int rn = (r + 3 < 8) ? (r + 3) : 7;  // clamped, branch-free
      LOADROW(rbase + rn, kB0, kB1, vB0, vB1);
    }
  }
#undef LOADROW

#pragma unroll
  for (int nt = 0; nt < 4; nt++) {
    lsum[nt] += __shfl_xor(lsum[nt], 16, 64);
    lsum[nt] += __shfl_xor(lsum[nt], 32, 64);
  }

  float* mO = (float*)lds;                 // [oct][32ch][64q]  32 KB
  float* mL = (float*)(lds + 16384);       // [oct][64q]  1 KB
  __syncthreads();  // all Pw reads done before overwrite
#pragma unroll
  for (int mt = 0; mt < 2; mt++)
#pragma unroll
    for (int nt = 0; nt < 4; nt++)
#pragma unroll
      for (int r = 0; r < 4; r++)
        mO[oct * 2048 + (16 * mt + quad * 4 + r) * 64 + 16 * nt + l15] = Oacc[mt][nt][r];
  if (quad == 0) {
#pragma unroll
    for (int nt = 0; nt < 4; nt++) mL[oct * 64 + nt * 16 + l15] = lsum[nt];
  }
  __syncthreads();
  {
    int q = threadIdx.x & 63;
    int cg = threadIdx.x >> 6;  // 0..3 -> 8 ch each
    float inv = 1.0f / (mL[q] + mL[64 + q] + mL[128 + q] + mL[192 + q]);
    float* ob = o + (((size_t)(b * 100 + n)) * 128 + h * 32 + cg * 8) * 64 + q;
#pragma unroll
    for (int e = 0; e < 8; e++) {
      int ch = cg * 8 + e;
      float s = mO[ch * 64 + q] + mO[2048 + ch * 64 + q] +
                mO[4096 + ch * 64 + q] + mO[6144 + ch * 64 + q];
      ob[(size_t)e * 64] = s * inv;
    }
  }
}

// ---------------------------------------------------------------------------
// Reverse: scatter-average overlapping 8x8 windows (step 6) into (2,128,62,62)
// ---------------------------------------------------------------------------
__global__ void reverse_kernel(const float* __restrict__ win, float* __restrict__ out) {
  int i = blockIdx.x * 256 + threadIdx.x;
  const int total = 2 * 128 * HSW;
  if (i >= total) return;
  int x = i % HS;
  int t = i / HS;
  int y = t % HS;
  t /= HS;
  int c = t % 128;
  int b = t / 128;
  int wi0 = (y >= 7) ? (y - 2) / 6 : 0;
  int wi1 = min(9, y / 6);
  int wj0 = (x >= 7) ? (x - 2) / 6 : 0;
  int wj1 = min(9, x / 6);
  float s = 0.0f;
  for (int wi = wi0; wi <= wi1; wi++)
    for (int wj = wj0; wj <= wj1; wj++) {
      int di = y - 6 * wi, dj = x - 6 * wj;
      s += win[(((size_t)(b * 100 + wi * 10 + wj)) * 128 + c) * 64 + di * 8 + dj];
    }
  float cnt = (float)((wi1 - wi0 + 1) * (wj1 - wj0 + 1));
  out[i] = s / cnt;
}

// ---------------------------------------------------------------------------
extern "C" void kernel_launch(void* const* d_in, const int* in_sizes, int n_in,
                              void* d_out, int out_size, void* d_ws, size_t ws_size,
                              hipStream_t stream) {
  const float* x      = (const float*)d_in[0];
  const float* sp     = (const float*)d_in[1];
  const float* w_pos  = (const float*)d_in[2];
  const float* b_pos  = (const float*)d_in[3];
  const float* w_q    = (const float*)d_in[4];
  const float* w_qdw  = (const float*)d_in[5];
  const float* w_kv   = (const float*)d_in[6];
  const float* w_kvdw = (const float*)d_in[7];
  const float* w_out  = (const float*)d_in[8];
  float* out = (float*)d_out;

  const size_t N_x   = (size_t)2 * 128 * HXW;   // 15,745,024 (shorts for kT/xpb)
  const size_t N_vp  = (size_t)2 * 128 * HXWP;  // 16,252,928 (padded vv, shorts)
  const size_t N_s   = (size_t)2 * 128 * HSW;
  const size_t N_att = (size_t)2 * 100 * 128 * 64;

  float* ws = (float*)d_ws;
  // shorts-based layout (all counts even -> float-aligned):
  unsigned short* xpb = (unsigned short*)ws;          // N_x shorts, dead after step 5
  unsigned short* kT  = (unsigned short*)ws;          // N_x shorts (overwrites xpb)
  unsigned short* vv  = kT + N_x;                     // N_vp shorts (padded rows)
  unsigned short* tkv = vv + N_vp;                    // 2*N_x shorts
  float* att = (float*)tkv;                           // reuse (tkv dead after step 6)
  float* rev = att + N_att;
  float* spp = (float*)(tkv + 2 * N_x);
  float* tq  = spp + N_s;
  unsigned short* qn  = (unsigned short*)(tq + N_s);  // N_s shorts
  unsigned short* wkb = qn + N_s;                     // 32768 shorts
  (void)ws_size; (void)in_sizes; (void)n_in; (void)out_size;

  // 0. wkb = bf16(w_kv)
  cvt_bf16_kernel<<<128, 256, 0, stream>>>(w_kv, wkb, 256 * 128);
  // 1. xpb = bf16(x + dwconv3(x, w_pos, b_pos))   (bf16 NCHW), 8px x 2rows/thread
  {
    int total = 2 * 128 * 124 * 31;
    dwconv8x2_bf16_kernel<<<(total + 255) / 256, 256, 0, stream>>>(x, w_pos, b_pos, xpb, total);
  }
  // 2. spp = sp + dwconv3(sp, w_pos, b_pos)
  {
    int total = (int)N_s;
    dwconv3_kernel<<<(total + 255) / 256, 256, 0, stream>>>(sp, w_pos, b_pos, spp, 128, HS, HS, total, 1);
  }
  // 3. tq = conv1(spp, w_q)
  {
    int HW = HSW;
    dim3 grid((HW + 63) / 64, 2, 2);
    conv1_kernel<128><<<grid, 256, 0, stream>>>(spp, w_q, tq, HW);
  }
  // 4. qn = bf16_nhwc(dwconv3(tq, w_qdw)) * 32^-0.5
  {
    int total = (int)N_s;
    dwconv_q_kernel<<<(total + 255) / 256, 256, 0, stream>>>(tq, w_qdw, qn, total);
  }
  // 5. tkv = bf16_nhwc(mfma_conv1(xpb, wkb))   (xpb dead after)
  {
    dim3 grid(HXW / 64, 2);
    conv1_kv_mfma_kernel<<<grid, 256, 0, stream>>>(xpb, wkb, tkv);
  }
  // 6. kT (NHWC) + vv (NCHW padded) = bf16(dwconv3(tkv, w_kvdw)) (overwrites xpb)
  {
    dim3 grid(496, 2);
    dwconv_kv_kernel<<<grid, 512, 0, stream>>>(tkv, w_kvdw, kT, vv);
  }
  // 7. attention -> att (2,100,128,64)   (800 one-head blocks, XCD-swizzled)
  {
    attn_mfma_kernel<<<800, 256, 0, stream>>>(qn, kT, vv, att);
  }
  // 8. rev = reverse(att)
  {
    int total = (int)N_s;
    reverse_kernel<<<(total + 255) / 256, 256, 0, stream>>>(att, rev);
  }
  // 9. out = conv1(rev, w_out)
  {
    int HW = HSW;
    dim3 grid((HW + 63) / 64, 2, 2);
    conv1_kernel<128><<<grid, 256, 0, stream>>>(rev, w_out, out, HW);
  }
}

// Round 12
// 252.047 us; speedup vs baseline: 1.0600x; 1.0206x over previous
//
#include <hip/hip_runtime.h>
#include <cstdint>

#define HS 62
#define HX 248
#define HXW (HX * HX)  // 61504
#define HSW (HS * HS)  // 3844
#define HXP 256        // padded row stride for vv (128-B aligned rows)
#define HXWP (HX * HXP)  // 63488 padded plane

typedef __attribute__((ext_vector_type(8))) short bf16x8;
typedef __attribute__((ext_vector_type(4))) float f32x4;
typedef __attribute__((ext_vector_type(2))) float f32x2;

static __device__ __forceinline__ unsigned short f2bf(float f) {
  uint32_t u = __builtin_bit_cast(uint32_t, f);
  u += 0x7fff + ((u >> 16) & 1);  // RNE
  return (unsigned short)(u >> 16);
}
static __device__ __forceinline__ float bf2f(unsigned short u) {
  uint32_t x = (uint32_t)u << 16;
  return __builtin_bit_cast(float, x);
}

// packed fp32 FMA: acc = a*b + acc (2 lanes of fp32, CDNA v_pk_fma_f32)
static __device__ __forceinline__ void pkfma(f32x2& acc, f32x2 a, f32x2 b) {
  asm("v_pk_fma_f32 %0, %1, %2, %0" : "+v"(acc) : "v"(a), "v"(b));
}
// packed f32->bf16 RNE convert: returns (bf16(lo) | bf16(hi)<<16)
static __device__ __forceinline__ uint32_t cvtpk(float lo, float hi) {
  uint32_t r;
  asm("v_cvt_pk_bf16_f32 %0, %1, %2" : "=v"(r) : "v"(lo), "v"(hi));
  return r;
}
// unpack u32 holding 2 bf16 -> packed f32 pair
static __device__ __forceinline__ f32x2 unp(uint32_t u) {
  f32x2 r;
  r.x = __builtin_bit_cast(float, u << 16);
  r.y = __builtin_bit_cast(float, u & 0xffff0000u);
  return r;
}

// ===========================================================================
// Device bodies (verbatim math from the round-6 kernels)
// ===========================================================================

// --- step 1: depthwise 3x3 x-path, 8 px x 2 rows per thread -> bf16 NCHW ---
static __device__ void dwconv8x2_body(const float* __restrict__ x,
                                      const float* __restrict__ w,
                                      const float* __restrict__ bias,
                                      unsigned short* __restrict__ y, int i) {
  int wq = (i % 31) * 8;
  int t = i / 31;
  int hp = t % 124;
  int bc = t / 124;
  int c = bc & 127;
  int hy = hp * 2;
  const float* xb = x + (size_t)bc * HXW;
  const float* wc = w + c * 9;
  float bv = bias[c];

  float rm1[10], r0[10], r1[10], r2[10];
  auto loadrow = [&](int h2, float (&r)[10]) {
    const float* row = xb + (size_t)h2 * HX + wq;
    float4 a = *(const float4*)row;
    float4 b2 = *(const float4*)(row + 4);
    r[1] = a.x;  r[2] = a.y;  r[3] = a.z;  r[4] = a.w;
    r[5] = b2.x; r[6] = b2.y; r[7] = b2.z; r[8] = b2.w;
    r[0] = (wq > 0) ? row[-1] : 0.0f;
    r[9] = (wq + 8 < HX) ? row[8] : 0.0f;
  };
  loadrow((hy > 0) ? hy - 1 : 0, rm1);
  loadrow(hy, r0);
  loadrow(hy + 1, r1);
  loadrow((hy + 2 < HX) ? hy + 2 : HX - 1, r2);
  if (hp == 0) {
#pragma unroll
    for (int k = 0; k < 10; k++) rm1[k] = 0.0f;
  }
  if (hp == 123) {
#pragma unroll
    for (int k = 0; k < 10; k++) r2[k] = 0.0f;
  }

  float w0 = wc[0], w1 = wc[1], w2 = wc[2];
  float w3 = wc[3], w4 = wc[4], w5 = wc[5];
  float w6 = wc[6], w7 = wc[7], w8 = wc[8];

  float o0[8], o1[8];
#pragma unroll
  for (int k = 0; k < 8; k++) {
    float s = bv;
    s += w0 * rm1[k]; s += w1 * rm1[k + 1]; s += w2 * rm1[k + 2];
    s += w3 * r0[k];  s += w4 * r0[k + 1];  s += w5 * r0[k + 2];
    s += w6 * r1[k];  s += w7 * r1[k + 1];  s += w8 * r1[k + 2];
    o0[k] = s + r0[k + 1];
    float u = bv;
    u += w0 * r0[k]; u += w1 * r0[k + 1]; u += w2 * r0[k + 2];
    u += w3 * r1[k]; u += w4 * r1[k + 1]; u += w5 * r1[k + 2];
    u += w6 * r2[k]; u += w7 * r2[k + 1]; u += w8 * r2[k + 2];
    o1[k] = u + r1[k + 1];
  }
  uint4 d0, d1;
  d0.x = cvtpk(o0[0], o0[1]); d0.y = cvtpk(o0[2], o0[3]);
  d0.z = cvtpk(o0[4], o0[5]); d0.w = cvtpk(o0[6], o0[7]);
  d1.x = cvtpk(o1[0], o1[1]); d1.y = cvtpk(o1[2], o1[3]);
  d1.z = cvtpk(o1[4], o1[5]); d1.w = cvtpk(o1[6], o1[7]);
  unsigned short* yb = y + (size_t)bc * HXW + (size_t)hy * HX + wq;
  *(uint4*)yb = d0;
  *(uint4*)(yb + HX) = d1;
}

// --- step 2: depthwise 3x3 on sp (62x62), fp32, bias+residual ---
static __device__ void dwconv3sp_body(const float* __restrict__ x,
                                      const float* __restrict__ w,
                                      const float* __restrict__ bias,
                                      float* __restrict__ y, int i) {
  int wx = i % HS;
  int t = i / HS;
  int hy = t % HS;
  int bc = t / HS;
  int c = bc & 127;
  const float* xb = x + (size_t)bc * HSW;
  const float* wc = w + c * 9;
  float s = bias[c];
  for (int di = -1; di <= 1; di++) {
    int h2 = hy + di;
    if (h2 < 0 || h2 >= HS) continue;
    for (int dj = -1; dj <= 1; dj++) {
      int w2 = wx + dj;
      if (w2 < 0 || w2 >= HS) continue;
      s += xb[(size_t)h2 * HS + w2] * wc[(di + 1) * 3 + (dj + 1)];
    }
  }
  s += xb[(size_t)hy * HS + wx];
  y[i] = s;
}

// --- step 4: depthwise 3x3 q path: fp32 -> bf16 NHWC, pre-scaled ---
static __device__ void dwconv_q_body(const float* __restrict__ x,
                                     const float* __restrict__ w,
                                     unsigned short* __restrict__ qn, int i) {
  int wx = i % HS;
  int t = i / HS;
  int hy = t % HS;
  int bc = t / HS;
  int c = bc & 127;
  int b = bc >> 7;
  const float* xb = x + (size_t)bc * HSW;
  const float* wc = w + c * 9;
  float s = 0.0f;
  for (int di = -1; di <= 1; di++) {
    int h2 = hy + di;
    if (h2 < 0 || h2 >= HS) continue;
    for (int dj = -1; dj <= 1; dj++) {
      int w2 = wx + dj;
      if (w2 < 0 || w2 >= HS) continue;
      s += xb[(size_t)h2 * HS + w2] * wc[(di + 1) * 3 + (dj + 1)];
    }
  }
  qn[((size_t)(b * HSW + hy * HS + wx)) * 128 + c] = f2bf(s * 0.17677669529663688f);
}

// --- step 5: MFMA 1x1 conv kv path (LDS-staged weights), one block's work ---
static __device__ void conv1_kv_body(const unsigned short* __restrict__ xpb,
                                     const unsigned short* __restrict__ wkb,
                                     unsigned short* __restrict__ y,
                                     int bx, int b, char* smem) {
  unsigned short* bufA = (unsigned short*)smem;            // 64*136
  unsigned short* bufW = bufA + 64 * 136;                  // 64*136
  int p0 = bx * 64;
  int tid = threadIdx.x;
  int wave = tid >> 6, lane = tid & 63, quad = lane >> 4, l15 = lane & 15;

  {
    int c = tid >> 1, half = tid & 1;
    const unsigned short* src = xpb + ((size_t)(b * 128 + c)) * HXW + p0 + half * 32;
#pragma unroll
    for (int j = 0; j < 8; j++) {
      uint2 v = *(const uint2*)(src + j * 4);
      int px = half * 32 + j * 4;
      bufA[(px + 0) * 136 + c] = (unsigned short)(v.x & 0xffff);
      bufA[(px + 1) * 136 + c] = (unsigned short)(v.x >> 16);
      bufA[(px + 2) * 136 + c] = (unsigned short)(v.y & 0xffff);
      bufA[(px + 3) * 136 + c] = (unsigned short)(v.y >> 16);
    }
  }
  __syncthreads();
  bf16x8 A[4];
#pragma unroll
  for (int kb = 0; kb < 4; kb++)
    A[kb] = __builtin_bit_cast(bf16x8,
        *(const uint4*)&bufA[(wave * 16 + l15) * 136 + kb * 32 + quad * 8]);

  const f32x4 zf = {0.f, 0.f, 0.f, 0.f};
#pragma unroll 1
  for (int h = 0; h < 2; h++) {
#pragma unroll 1
    for (int oq = 0; oq < 2; oq++) {
      __syncthreads();
      {
        int orow = tid >> 2;
        int cseg = (tid & 3) * 32;
        const unsigned short* src = wkb + (size_t)(h * 128 + oq * 64 + orow) * 128 + cseg;
        unsigned short* dst = &bufW[orow * 136 + cseg];
        *(uint4*)(dst)      = *(const uint4*)(src);
        *(uint4*)(dst + 8)  = *(const uint4*)(src + 8);
        *(uint4*)(dst + 16) = *(const uint4*)(src + 16);
        *(uint4*)(dst + 24) = *(const uint4*)(src + 24);
      }
      __syncthreads();
#pragma unroll
      for (int ot = 0; ot < 4; ot++) {
        const unsigned short* wrow = &bufW[(ot * 16 + l15) * 136 + quad * 8];
        f32x4 D = zf;
        D = __builtin_amdgcn_mfma_f32_16x16x32_bf16(A[0], __builtin_bit_cast(bf16x8, *(const uint4*)(wrow)),      D, 0, 0, 0);
        D = __builtin_amdgcn_mfma_f32_16x16x32_bf16(A[1], __builtin_bit_cast(bf16x8, *(const uint4*)(wrow + 32)), D, 0, 0, 0);
        D = __builtin_amdgcn_mfma_f32_16x16x32_bf16(A[2], __builtin_bit_cast(bf16x8, *(const uint4*)(wrow + 64)), D, 0, 0, 0);
        D = __builtin_amdgcn_mfma_f32_16x16x32_bf16(A[3], __builtin_bit_cast(bf16x8, *(const uint4*)(wrow + 96)), D, 0, 0, 0);
#pragma unroll
        for (int r = 0; r < 4; r++)
          bufA[(wave * 16 + quad * 4 + r) * 136 + (oq * 4 + ot) * 16 + l15] = f2bf(D[r]);
      }
    }
    __syncthreads();
    {
      int px = tid >> 2, og = (tid & 3) * 32;
      const uint4* srcp = (const uint4*)&bufA[px * 136 + og];
      uint4* dstp = (uint4*)(y + ((size_t)b * HXW + p0 + px) * 256 + h * 128 + og);
#pragma unroll
      for (int j = 0; j < 4; j++) dstp[j] = srcp[j];
    }
  }
}

// --- 1x1 conv tiled SGEMM body (fp32), one block's work ---
static __device__ void conv1_body(const float* __restrict__ x,
                                  const float* __restrict__ w,
                                  float* __restrict__ y, int HW, int O,
                                  int bx, int by, int bz, char* smem) {
  constexpr int K = 128;
  constexpr int BK = 32;
  float (*ws_s)[64] = (float(*)[64])smem;
  float (*xs_s)[64] = (float(*)[64])(smem + BK * 64 * sizeof(float));
  int b = bz;
  int o0 = by * 64;
  int p0 = bx * 64;
  const float* xb = x + (size_t)b * K * HW;
  int tx = threadIdx.x & 15;
  int ty = threadIdx.x >> 4;
  float acc[4][4] = {};
  int lo = threadIdx.x >> 2;
  int lk = (threadIdx.x & 3) * 8;
  int lc = threadIdx.x >> 3;
  int lp = (threadIdx.x & 7) * 8;

  for (int k0 = 0; k0 < K; k0 += BK) {
    __syncthreads();
    {
      const float* wp = w + (size_t)(o0 + lo) * K + k0 + lk;
      float4 a = *(const float4*)wp;
      float4 bq = *(const float4*)(wp + 4);
      ws_s[lk + 0][lo] = a.x;  ws_s[lk + 1][lo] = a.y;
      ws_s[lk + 2][lo] = a.z;  ws_s[lk + 3][lo] = a.w;
      ws_s[lk + 4][lo] = bq.x; ws_s[lk + 5][lo] = bq.y;
      ws_s[lk + 6][lo] = bq.z; ws_s[lk + 7][lo] = bq.w;
    }
    {
      int p = p0 + lp;
      const float* xp = xb + (size_t)(k0 + lc) * HW;
      float4 a, bq;
      if (p + 7 < HW) {
        a = *(const float4*)(xp + p);
        bq = *(const float4*)(xp + p + 4);
      } else {
        float tv[8];
#pragma unroll
        for (int j = 0; j < 8; j++) tv[j] = (p + j < HW) ? xp[p + j] : 0.0f;
        a = make_float4(tv[0], tv[1], tv[2], tv[3]);
        bq = make_float4(tv[4], tv[5], tv[6], tv[7]);
      }
      *(float4*)&xs_s[lc][lp] = a;
      *(float4*)&xs_s[lc][lp + 4] = bq;
    }
    __syncthreads();
#pragma unroll
    for (int k = 0; k < BK; k++) {
      float4 wv = *(const float4*)&ws_s[k][ty * 4];
      float4 xv = *(const float4*)&xs_s[k][tx * 4];
      acc[0][0] += wv.x * xv.x; acc[0][1] += wv.x * xv.y; acc[0][2] += wv.x * xv.z; acc[0][3] += wv.x * xv.w;
      acc[1][0] += wv.y * xv.x; acc[1][1] += wv.y * xv.y; acc[1][2] += wv.y * xv.z; acc[1][3] += wv.y * xv.w;
      acc[2][0] += wv.z * xv.x; acc[2][1] += wv.z * xv.y; acc[2][2] += wv.z * xv.z; acc[2][3] += wv.z * xv.w;
      acc[3][0] += wv.w * xv.x; acc[3][1] += wv.w * xv.y; acc[3][2] += wv.w * xv.z; acc[3][3] += wv.w * xv.w;
    }
  }
  int p = p0 + tx * 4;
  float* yb = y + (size_t)b * O * HW + (size_t)(o0 + ty * 4) * HW;
#pragma unroll
  for (int j = 0; j < 4; j++) {
    float* yr = yb + (size_t)j * HW + p;
    if (p + 3 < HW) {
      *(float4*)yr = make_float4(acc[j][0], acc[j][1], acc[j][2], acc[j][3]);
    } else {
#pragma unroll
      for (int e = 0; e < 4; e++) if (p + e < HW) yr[e] = acc[j][e];
    }
  }
}

// --- step 6: fused depthwise 3x3 K/V, one block's work ---
template <bool VT, bool VB>
static __device__ __forceinline__ void dwkv_rowpair(
    const unsigned short* __restrict__ rm1, const unsigned short* __restrict__ r0,
    const unsigned short* __restrict__ r1, const unsigned short* __restrict__ r2,
    const f32x2 (&wp)[9], int px0, f32x2 (&a0)[8], f32x2 (&a1)[8]) {
  const f32x2 z2 = {0.f, 0.f};
#pragma unroll
  for (int p = 0; p < 8; p++) { a0[p] = z2; a1[p] = z2; }
#pragma unroll
  for (int j = 0; j < 10; j++) {
    int xcol = px0 - 1 + j;
    int xc = xcol;
    if (j == 0) xc = (xcol < 0) ? 0 : xcol;
    if (j == 9) xc = (xcol > HX - 1) ? HX - 1 : xcol;
    size_t off = (size_t)xc * 256;
    uint32_t um1 = 0, u0, u1, u2 = 0;
    u0 = *(const uint32_t*)(r0 + off);
    u1 = *(const uint32_t*)(r1 + off);
    if constexpr (VT) um1 = *(const uint32_t*)(rm1 + off);
    if constexpr (VB) u2 = *(const uint32_t*)(r2 + off);
    if (j == 0 || j == 9) {
      bool oob = (j == 0) ? (xcol < 0) : (xcol > HX - 1);
      if (oob) { um1 = 0u; u0 = 0u; u1 = 0u; u2 = 0u; }
    }
    f32x2 dm1, d0 = unp(u0), d1 = unp(u1), d2;
    if constexpr (VT) dm1 = unp(um1);
    if constexpr (VB) d2 = unp(u2);
    if (j <= 7) {
      if constexpr (VT) pkfma(a0[j], wp[0], dm1);
      pkfma(a0[j], wp[3], d0);
      pkfma(a0[j], wp[6], d1);
      pkfma(a1[j], wp[0], d0);
      pkfma(a1[j], wp[3], d1);
      if constexpr (VB) pkfma(a1[j], wp[6], d2);
    }
    if (j >= 1 && j <= 8) {
      if constexpr (VT) pkfma(a0[j - 1], wp[1], dm1);
      pkfma(a0[j - 1], wp[4], d0);
      pkfma(a0[j - 1], wp[7], d1);
      pkfma(a1[j - 1], wp[1], d0);
      pkfma(a1[j - 1], wp[4], d1);
      if constexpr (VB) pkfma(a1[j - 1], wp[7], d2);
    }
    if (j >= 2) {
      if constexpr (VT) pkfma(a0[j - 2], wp[2], dm1);
      pkfma(a0[j - 2], wp[5], d0);
      pkfma(a0[j - 2], wp[8], d1);
      pkfma(a1[j - 2], wp[2], d0);
      pkfma(a1[j - 2], wp[5], d1);
      if constexpr (VB) pkfma(a1[j - 2], wp[8], d2);
    }
  }
}

#define VTS 72                    // vt channel stride (shorts)
#define VTROW (128 * VTS + 16)    // vt row stride (shorts)

static __device__ void dwconv_kv_body(const unsigned short* __restrict__ tkv,
                                      const float* __restrict__ w,
                                      unsigned short* __restrict__ kT,
                                      unsigned short* __restrict__ vv,
                                      int fid, int b, unsigned short* vt) {
  int xcd = fid & 7, slot = fid >> 3;
  int gi = xcd * 62 + slot;          // 0..495
  int strip = gi / 124;              // 0..3
  int g = gi % 124;                  // row-pair index
  int x0 = strip * 64;
  int tid = threadIdx.x;
  int cl = tid & 127;
  int pg = tid >> 7;
  int ch0 = cl * 2;
  int hy0 = g * 2;

  f32x2 wp[9];
#pragma unroll
  for (int t = 0; t < 9; t++) {
    wp[t].x = w[ch0 * 9 + t];
    wp[t].y = w[(ch0 + 1) * 9 + t];
  }

  const unsigned short* r0 = tkv + (size_t)b * HXW * 256 + (size_t)hy0 * (HX * 256) + ch0;
  const unsigned short* r1 = r0 + HX * 256;
  const unsigned short* rm1 = r0 - HX * 256;
  const unsigned short* r2 = r1 + HX * 256;
  bool isK = (cl < 64);
  int c0 = ch0 - 128;

#pragma unroll 1
  for (int half = 0; half < 2; half++) {
    int px0 = x0 + pg * 16 + half * 8;
    if (px0 < HX) {
      f32x2 a0[8], a1[8];
      if (g == 0)        dwkv_rowpair<false, true >(rm1, r0, r1, r2, wp, px0, a0, a1);
      else if (g == 123) dwkv_rowpair<true,  false>(rm1, r0, r1, r2, wp, px0, a0, a1);
      else               dwkv_rowpair<true,  true >(rm1, r0, r1, r2, wp, px0, a0, a1);

      if (isK) {
        unsigned short* kb0 = kT + ((size_t)b * HXW + (size_t)hy0 * HX + px0) * 128 + ch0;
        unsigned short* kb1 = kb0 + (size_t)HX * 128;
#pragma unroll
        for (int p = 0; p < 8; p++) {
          *(uint32_t*)(kb0 + (size_t)p * 128) = cvtpk(a0[p].x, a0[p].y);
          *(uint32_t*)(kb1 + (size_t)p * 128) = cvtpk(a1[p].x, a1[p].y);
        }
      } else {
        int pxr = pg * 16 + half * 8;
        unsigned short* v0 = vt + c0 * VTS + pxr;
        unsigned short* v1 = v0 + VTS;
        uint2 d;
        d.x = cvtpk(a0[0].x, a0[1].x); d.y = cvtpk(a0[2].x, a0[3].x);
        *(uint2*)(v0) = d;
        d.x = cvtpk(a0[4].x, a0[5].x); d.y = cvtpk(a0[6].x, a0[7].x);
        *(uint2*)(v0 + 4) = d;
        d.x = cvtpk(a0[0].y, a0[1].y); d.y = cvtpk(a0[2].y, a0[3].y);
        *(uint2*)(v1) = d;
        d.x = cvtpk(a0[4].y, a0[5].y); d.y = cvtpk(a0[6].y, a0[7].y);
        *(uint2*)(v1 + 4) = d;
        d.x = cvtpk(a1[0].x, a1[1].x); d.y = cvtpk(a1[2].x, a1[3].x);
        *(uint2*)(v0 + VTROW) = d;
        d.x = cvtpk(a1[4].x, a1[5].x); d.y = cvtpk(a1[6].x, a1[7].x);
        *(uint2*)(v0 + VTROW + 4) = d;
        d.x = cvtpk(a1[0].y, a1[1].y); d.y = cvtpk(a1[2].y, a1[3].y);
        *(uint2*)(v1 + VTROW) = d;
        d.x = cvtpk(a1[4].y, a1[5].y); d.y = cvtpk(a1[6].y, a1[7].y);
        *(uint2*)(v1 + VTROW + 4) = d;
      }
    }
  }
  __syncthreads();
  {
    int ch = tid >> 2;
    int row = (tid >> 1) & 1;
    int ph = (tid & 1) * 32;
    const unsigned short* srcv = vt + row * VTROW + ch * VTS + ph;
    unsigned short* dst = vv + (size_t)(b * 128 + ch) * HXWP + (size_t)(hy0 + row) * HXP + x0 + ph;
#pragma unroll
    for (int j = 0; j < 4; j++)
      *(uint4*)(dst + j * 8) = *(const uint4*)(srcv + j * 8);
  }
}

// ===========================================================================
// Combined dispatch kernels
// ===========================================================================
#define NB_DW8 3844   // 2*128*124*31 / 256
#define NB_DW3 3844   // 2*128*62*62 / 256
#define NB_CVT 128    // 32768 / 256

// combo A = step1 (dwconv8x2) || step2 (dwconv3 sp) || step0 (cvt w_kv)
__global__ __launch_bounds__(256) void comboA_kernel(
    const float* __restrict__ x, const float* __restrict__ w_pos,
    const float* __restrict__ b_pos, unsigned short* __restrict__ xpb,
    const float* __restrict__ sp, float* __restrict__ spp,
    const float* __restrict__ w_kv, unsigned short* __restrict__ wkb) {
  int bid = blockIdx.x, tid = threadIdx.x;
  if (bid < NB_DW8) {
    int i = bid * 256 + tid;
    dwconv8x2_body(x, w_pos, b_pos, xpb, i);
  } else if (bid < NB_DW8 + NB_DW3) {
    int i = (bid - NB_DW8) * 256 + tid;
    dwconv3sp_body(sp, w_pos, b_pos, spp, i);
  } else {
    int i = (bid - NB_DW8 - NB_DW3) * 256 + tid;
    if (i < 32768) wkb[i] = f2bf(w_kv[i]);
  }
}

// combo B = step5 (conv1_kv mfma, 1922 blocks) || step3 (conv1 q, 244 blocks)
__global__ __launch_bounds__(256) void comboB_kernel(
    const unsigned short* __restrict__ xpb, const unsigned short* __restrict__ wkb,
    unsigned short* __restrict__ tkv,
    const float* __restrict__ spp, const float* __restrict__ w_q,
    float* __restrict__ tq) {
  __shared__ __align__(16) char smem[64 * 136 * 2 * 2];  // 34,816 B (max)
  int bid = blockIdx.x;
  if (bid < 1922) {
    conv1_kv_body(xpb, wkb, tkv, bid % 961, bid / 961, smem);
  } else {
    int cid = bid - 1922;
    conv1_body(spp, w_q, tq, HSW, 128, cid % 61, (cid / 61) % 2, cid / 122, smem);
  }
}

// combo C = step6 (dwconv_kv, 992 blocks @512) || step4 (dwconv_q, 1922 blocks)
__global__ __launch_bounds__(512) __attribute__((amdgpu_waves_per_eu(4)))
void comboC_kernel(const unsigned short* __restrict__ tkv,
                   const float* __restrict__ w_kvdw,
                   unsigned short* __restrict__ kT, unsigned short* __restrict__ vv,
                   const float* __restrict__ tq, const float* __restrict__ w_qdw,
                   unsigned short* __restrict__ qn) {
  __shared__ __align__(16) unsigned short vt[2 * VTROW];  // 36,928 B
  int bid = blockIdx.x;
  if (bid < 992) {
    dwconv_kv_body(tkv, w_kvdw, kT, vv, bid % 496, bid / 496, vt);
  } else {
    int i = (bid - 992) * 512 + threadIdx.x;
    if (i < 2 * 128 * HSW) dwconv_q_body(tq, w_qdw, qn, i);
  }
}

// ---------------------------------------------------------------------------
// step 9: 1x1 conv (standalone wrapper over conv1_body)
// ---------------------------------------------------------------------------
__global__ __launch_bounds__(256) void conv1_out_kernel(const float* __restrict__ x,
                                                        const float* __restrict__ w,
                                                        float* __restrict__ y, int HW) {
  __shared__ __align__(16) char smem[2 * 32 * 64 * 4];  // 16,384 B
  conv1_body(x, w, y, HW, 128, blockIdx.x, blockIdx.y, blockIdx.z, smem);
}

// ---------------------------------------------------------------------------
// MFMA windowed attention v3 — one head per block (unchanged).
// ---------------------------------------------------------------------------
__global__ __launch_bounds__(256) void attn_mfma_kernel(
    const unsigned short* __restrict__ qn,   // (2,62,62,128) bf16, pre-scaled
    const unsigned short* __restrict__ kT,   // (2,248,248,128) bf16 NHWC
    const unsigned short* __restrict__ vp,   // (2,128,248,256p) bf16 NCHW padded
    float* __restrict__ o) {                 // (2,100,128,64)
  int fid = blockIdx.x;
  int xcd = fid & 7, slot = fid >> 3;        // slot 0..99
  int lin = xcd * 100 + slot;
  int n = lin % 100;
  int bh = lin / 100;                        // 0..7
  int h = bh & 3, b = bh >> 2;
  int wi = n / 10, wj = n % 10;
  int wave = threadIdx.x >> 6;               // oct 0..3
  int oct = wave;
  int lane = threadIdx.x & 63;
  int quad = lane >> 4;
  int l15 = lane & 15;
  int y0 = 24 * wi, x0 = 24 * wj;

  __shared__ __align__(16) unsigned short lds[16896];  // 33,792 B
  unsigned short* Pw = lds + wave * 2560;              // [q][40keys] 5KB/wave

  bf16x8 QB[4];
#pragma unroll
  for (int nt = 0; nt < 4; nt++) {
    int qq = nt * 16 + l15;
    int qy = 6 * wi + (qq >> 3), qx = 6 * wj + (qq & 7);
    QB[nt] = __builtin_bit_cast(bf16x8,
        *(const uint4*)(qn + ((size_t)(b * HSW + qy * HS + qx)) * 128 + h * 32 + quad * 8));
  }

  f32x4 Oacc[2][4];
#pragma unroll
  for (int a = 0; a < 2; a++)
#pragma unroll
    for (int c = 0; c < 4; c++) Oacc[a][c] = f32x4{0.f, 0.f, 0.f, 0.f};
  float lsum[4] = {0.f, 0.f, 0.f, 0.f};

  const unsigned short* kb = kT + (size_t)b * HXW * 128 + h * 32;
  const unsigned short* vb = vp + ((size_t)(b * 128 + h * 32)) * HXWP;
  const f32x4 zf = {0.f, 0.f, 0.f, 0.f};

#define LOADROW(r, K0, K1, V0, V1)                                              \
  {                                                                             \
    int y = y0 + (r);                                                           \
    const unsigned short* krow = kb + ((size_t)(y * HX + x0)) * 128;            \
    K0 = *(const uint4*)(krow + (size_t)l15 * 128 + quad * 8);                  \
    K1 = *(const uint4*)(krow + (size_t)(16 + l15) * 128 + quad * 8);           \
    const unsigned short* vrow = vb + (size_t)y * HXP + x0 + quad * 8;          \
    V0 = *(const uint4*)(vrow + (size_t)l15 * HXWP);                            \
    V1 = *(const uint4*)(vrow + (size_t)(16 + l15) * HXWP);                     \
  }

  auto compute = [&](uint4 k0, uint4 k1, uint4 v0, uint4 v1) {
    bf16x8 KA0 = __builtin_bit_cast(bf16x8, k0);
    bf16x8 KA1 = __builtin_bit_cast(bf16x8, k1);
    bf16x8 VA0 = __builtin_bit_cast(bf16x8, v0);
    bf16x8 VA1 = __builtin_bit_cast(bf16x8, v1);
    f32x4 S[2][4];
#pragma unroll
    for (int nt = 0; nt < 4; nt++) {
      S[0][nt] = __builtin_amdgcn_mfma_f32_16x16x32_bf16(KA0, QB[nt], zf, 0, 0, 0);
      S[1][nt] = __builtin_amdgcn_mfma_f32_16x16x32_bf16(KA1, QB[nt], zf, 0, 0, 0);
    }
#pragma unroll
    for (int nt = 0; nt < 4; nt++) {
      float pv[2][4];
      float cs = 0.f;
#pragma unroll
      for (int mt = 0; mt < 2; mt++)
#pragma unroll
        for (int r = 0; r < 4; r++) {
          pv[mt][r] = __expf(S[mt][nt][r]);
          cs += pv[mt][r];
        }
      lsum[nt] += cs;
#pragma unroll
      for (int mt = 0; mt < 2; mt++) {
        uint2 d;
        d.x = (uint32_t)f2bf(pv[mt][0]) | ((uint32_t)f2bf(pv[mt][1]) << 16);
        d.y = (uint32_t)f2bf(pv[mt][2]) | ((uint32_t)f2bf(pv[mt][3]) << 16);
        *(uint2*)(Pw + (16 * nt + l15) * 40 + 16 * mt + quad * 4) = d;
      }
    }
#pragma unroll
    for (int nt = 0; nt < 4; nt++) {
      bf16x8 PB = __builtin_bit_cast(bf16x8, *(const uint4*)(Pw + (16 * nt + l15) * 40 + quad * 8));
      Oacc[0][nt] = __builtin_amdgcn_mfma_f32_16x16x32_bf16(VA0, PB, Oacc[0][nt], 0, 0, 0);
      Oacc[1][nt] = __builtin_amdgcn_mfma_f32_16x16x32_bf16(VA1, PB, Oacc[1][nt], 0, 0, 0);
    }
  };

  int rbase = oct * 8;
  uint4 kA0, kA1, vA0, vA1, kB0, kB1, vB0, vB1;
  LOADROW(rbase + 0, kA0, kA1, vA0, vA1);
  LOADROW(rbase + 1, kB0, kB1, vB0, vB1);
#pragma unroll 1
  for (int r = 0; r < 8; r += 2) {
    compute(kA0, kA1, vA0, vA1);
    {
      int rn = (r + 2 < 8) ? (r + 2) : 6;  // clamped, branch-free
      LOADROW(rbase + rn, kA0, kA1, vA0, vA1);
    }
    compute(kB0, kB1, vB0, vB1);
    {
      int rn = (r + 3 < 8) ? (r + 3) : 7;  // clamped, branch-free
      LOADROW(rbase + rn, kB0, kB1, vB0, vB1);
    }
  }
#undef LOADROW

#pragma unroll
  for (int nt = 0; nt < 4; nt++) {
    lsum[nt] += __shfl_xor(lsum[nt], 16, 64);
    lsum[nt] += __shfl_xor(lsum[nt], 32, 64);
  }

  float* mO = (float*)lds;                 // [oct][32ch][64q]  32 KB
  float* mL = (float*)(lds + 16384);       // [oct][64q]  1 KB
  __syncthreads();  // all Pw reads done before overwrite
#pragma unroll
  for (int mt = 0; mt < 2; mt++)
#pragma unroll
    for (int nt = 0; nt < 4; nt++)
#pragma unroll
      for (int r = 0; r < 4; r++)
        mO[oct * 2048 + (16 * mt + quad * 4 + r) * 64 + 16 * nt + l15] = Oacc[mt][nt][r];
  if (quad == 0) {
#pragma unroll
    for (int nt = 0; nt < 4; nt++) mL[oct * 64 + nt * 16 + l15] = lsum[nt];
  }
  __syncthreads();
  {
    int q = threadIdx.x & 63;
    int cg = threadIdx.x >> 6;  // 0..3 -> 8 ch each
    float inv = 1.0f / (mL[q] + mL[64 + q] + mL[128 + q] + mL[192 + q]);
    float* ob = o + (((size_t)(b * 100 + n)) * 128 + h * 32 + cg * 8) * 64 + q;
#pragma unroll
    for (int e = 0; e < 8; e++) {
      int ch = cg * 8 + e;
      float s = mO[ch * 64 + q] + mO[2048 + ch * 64 + q] +
                mO[4096 + ch * 64 + q] + mO[6144 + ch * 64 + q];
      ob[(size_t)e * 64] = s * inv;
    }
  }
}

// ---------------------------------------------------------------------------
// Reverse: scatter-average overlapping 8x8 windows into (2,128,62,62)
// ---------------------------------------------------------------------------
__global__ void reverse_kernel(const float* __restrict__ win, float* __restrict__ out) {
  int i = blockIdx.x * 256 + threadIdx.x;
  const int total = 2 * 128 * HSW;
  if (i >= total) return;
  int x = i % HS;
  int t = i / HS;
  int y = t % HS;
  t /= HS;
  int c = t % 128;
  int b = t / 128;
  int wi0 = (y >= 7) ? (y - 2) / 6 : 0;
  int wi1 = min(9, y / 6);
  int wj0 = (x >= 7) ? (x - 2) / 6 : 0;
  int wj1 = min(9, x / 6);
  float s = 0.0f;
  for (int wi = wi0; wi <= wi1; wi++)
    for (int wj = wj0; wj <= wj1; wj++) {
      int di = y - 6 * wi, dj = x - 6 * wj;
      s += win[(((size_t)(b * 100 + wi * 10 + wj)) * 128 + c) * 64 + di * 8 + dj];
    }
  float cnt = (float)((wi1 - wi0 + 1) * (wj1 - wj0 + 1));
  out[i] = s / cnt;
}

// ---------------------------------------------------------------------------
extern "C" void kernel_launch(void* const* d_in, const int* in_sizes, int n_in,
                              void* d_out, int out_size, void* d_ws, size_t ws_size,
                              hipStream_t stream) {
  const float* x      = (const float*)d_in[0];
  const float* sp     = (const float*)d_in[1];
  const float* w_pos  = (const float*)d_in[2];
  const float* b_pos  = (const float*)d_in[3];
  const float* w_q    = (const float*)d_in[4];
  const float* w_qdw  = (const float*)d_in[5];
  const float* w_kv   = (const float*)d_in[6];
  const float* w_kvdw = (const float*)d_in[7];
  const float* w_out  = (const float*)d_in[8];
  float* out = (float*)d_out;

  const size_t N_x   = (size_t)2 * 128 * HXW;   // 15,745,024 (shorts for kT/xpb)
  const size_t N_vp  = (size_t)2 * 128 * HXWP;  // 16,252,928 (padded vv, shorts)
  const size_t N_s   = (size_t)2 * 128 * HSW;
  const size_t N_att = (size_t)2 * 100 * 128 * 64;

  float* ws = (float*)d_ws;
  // shorts-based layout (all counts even -> float-aligned):
  unsigned short* xpb = (unsigned short*)ws;          // N_x shorts, dead after combo B
  unsigned short* kT  = (unsigned short*)ws;          // N_x shorts (overwrites xpb)
  unsigned short* vv  = kT + N_x;                     // N_vp shorts (padded rows)
  unsigned short* tkv = vv + N_vp;                    // 2*N_x shorts
  float* att = (float*)tkv;                           // reuse (tkv dead after combo C)
  float* rev = att + N_att;
  float* spp = (float*)(tkv + 2 * N_x);
  float* tq  = spp + N_s;
  unsigned short* qn  = (unsigned short*)(tq + N_s);  // N_s shorts
  unsigned short* wkb = qn + N_s;                     // 32768 shorts
  (void)ws_size; (void)in_sizes; (void)n_in; (void)out_size;

  // A: step1 (xpb) || step2 (spp) || step0 (wkb)
  comboA_kernel<<<NB_DW8 + NB_DW3 + NB_CVT, 256, 0, stream>>>(
      x, w_pos, b_pos, xpb, sp, spp, w_kv, wkb);
  // B: step5 (tkv; xpb dead after) || step3 (tq)
  comboB_kernel<<<1922 + 244, 256, 0, stream>>>(xpb, wkb, tkv, spp, w_q, tq);
  // C: step6 (kT, vv; overwrites xpb) || step4 (qn)
  comboC_kernel<<<992 + 1922, 512, 0, stream>>>(tkv, w_kvdw, kT, vv, tq, w_qdw, qn);
  // 7. attention -> att (800 one-head blocks, XCD-swizzled)
  attn_mfma_kernel<<<800, 256, 0, stream>>>(qn, kT, vv, att);
  // 8. rev = reverse(att)
  {
    int total = (int)N_s;
    reverse_kernel<<<(total + 255) / 256, 256, 0, stream>>>(att, rev);
  }
  // 9. out = conv1(rev, w_out)
  {
    dim3 grid((HSW + 63) / 64, 2, 2);
    conv1_out_kernel<<<grid, 256, 0, stream>>>(rev, w_out, out, HSW);
  }
}